// Round 11
// baseline (961.183 us; speedup 1.0000x reference)
//
#include <hip/hip_runtime.h>
#include <hip/hip_bf16.h>

typedef unsigned short u16;
typedef __bf16 bf16x8 __attribute__((ext_vector_type(8)));
typedef float f32x4 __attribute__((ext_vector_type(4)));

#define NB 4
#define NCAM 6
#define NBN 24
#define CIN 256
#define CC 64
#define ND 41
#define FH 16
#define FW 44
#define NX 200

// ---- workspace byte offsets (overlaid; max used 164,462,592 B) ----
#define WS_FEATT_HI 0ul
#define WS_FEATT_LO 8650752ul
#define WS_H1_HI    17301504ul
#define WS_H2_HI    34603008ul
#define WS_H1D      51904512ul
#define WS_BW1_HI   69206016ul
#define WS_BW1_LO   69353472ul
#define WS_BEV0     76302336ul
#define WS_CW1_HI   117262336ul
#define WS_CW1_LO   118441984ul
#define WS_CW2_HI   119621632ul
#define WS_CW2_LO   120801280ul
#define WS_CWL_HI   121980928ul
#define WS_CWL_LO   122013696ul
#define WS_DW1_HI   122046464ul
#define WS_DW1_LO   122177536ul
#define WS_DEP      122308608ul
#define WS_IMGT     125079552ul
#define WS_MATS     129404928ul
#define WS_FUSW_HI  129406656ul
#define WS_FUSW_LO  129414848ul
#define WS_BEV1_HI  0ul            // u16 [4*200*200*64]; fus->bev<64>; cam bufs dead
#define WS_HB1_HI   81920000ul     // u16 [4*200*200*128]; bev<64>->bev<128>
#define WS_HB2_HI   0ul            // u16 [4*200*200*128]; bev<128>->out (bev1 dead)
#define WS_BW2_HI   163840000ul
#define WS_BW2_LO   164134912ul
#define WS_BWL_HI   164429824ul
#define WS_BWL_LO   164446208ul

__device__ inline u16 f2bf_rne(float x) {
  unsigned u = __float_as_uint(x);
  unsigned r = u + 0x7fffu + ((u >> 16) & 1u);
  return (u16)(r >> 16);
}
__device__ inline float bf2f(u16 h) { return __uint_as_float(((unsigned)h) << 16); }
__device__ inline void split_bf(float x, u16& hi, u16& lo) {
  hi = f2bf_rne(x);
  lo = f2bf_rne(x - bf2f(hi));
}
__device__ inline f32x4 mfma16(bf16x8 a, bf16x8 b, f32x4 c) {
  return __builtin_amdgcn_mfma_f32_16x16x32_bf16(a, b, c, 0, 0, 0);
}
__device__ inline bf16x8 ld8(const u16* p) { return *(const bf16x8*)p; }

// ============ feat NCHW f32 -> NHWC hi/lo planes ============
__global__ __launch_bounds__(256) void featsplit(const float* __restrict__ in,
    u16* __restrict__ oh, u16* __restrict__ ol) {
  int nh = blockIdx.x;
  int n = nh >> 4, h = nh & 15;
  __shared__ float lds[256][44];
  int tid = threadIdx.x;
  for (int e = tid; e < 256 * 44; e += 256) {
    int ci = e / 44, w = e % 44;
    lds[ci][w] = in[((n * CIN + ci) * FH + h) * FW + w];
  }
  __syncthreads();
  for (int e = tid; e < 256 * 44; e += 256) {
    int w = e / 256, ci = e % 256;
    u16 hi, lo;
    split_bf(lds[ci][w], hi, lo);
    size_t o = ((size_t)((n * FH + h) * FW + w)) * 256 + ci;
    oh[o] = hi; ol[o] = lo;
  }
}

// ============ weight split 3x3 ============
__global__ __launch_bounds__(256) void wsplit3(const float* __restrict__ src,
    u16* __restrict__ dhi, u16* __restrict__ dlo, int CO, int CI_) {
  int idx = blockIdx.x * 256 + threadIdx.x;
  if (idx >= CO * CI_ * 9) return;
  int co = idx / (CI_ * 9);
  int r = idx % (CI_ * 9);
  int ci = r / 9, t = r % 9;
  u16 h, l;
  split_bf(src[idx], h, l);
  int o = (t * CO + co) * CI_ + ci;
  dhi[o] = h; dlo[o] = l;
}

// ============ weight split 1x1 ============
__global__ __launch_bounds__(256) void wsplit1(const float* __restrict__ src,
    u16* __restrict__ dhi, u16* __restrict__ dlo, int n) {
  int i = blockIdx.x * 256 + threadIdx.x;
  if (i >= n) return;
  u16 h, l;
  split_bf(src[i], h, l);
  dhi[i] = h; dlo[i] = l;
}

// ============ per-(b,n) matrices ============
__global__ void prep_mats(const float* __restrict__ rots, const float* __restrict__ intrins,
                          const float* __restrict__ post_rots, float* __restrict__ mats) {
  int bn = threadIdx.x;
  if (bn >= NBN) return;
  {
    const float* A = intrins + bn * 9;
    double a0=A[0],a1=A[1],a2=A[2],a3=A[3],a4=A[4],a5=A[5],a6=A[6],a7=A[7],a8=A[8];
    double det = a0*(a4*a8 - a5*a7) - a1*(a3*a8 - a5*a6) + a2*(a3*a7 - a4*a6);
    float inv[9];
    inv[0] = (float)((a4*a8 - a5*a7) / det);
    inv[1] = (float)((a2*a7 - a1*a8) / det);
    inv[2] = (float)((a1*a5 - a2*a4) / det);
    inv[3] = (float)((a5*a6 - a3*a8) / det);
    inv[4] = (float)((a0*a8 - a2*a6) / det);
    inv[5] = (float)((a2*a3 - a0*a5) / det);
    inv[6] = (float)((a3*a7 - a4*a6) / det);
    inv[7] = (float)((a1*a6 - a0*a7) / det);
    inv[8] = (float)((a0*a4 - a1*a3) / det);
    const float* R = rots + bn * 9;
    #pragma unroll
    for (int i = 0; i < 3; ++i)
      #pragma unroll
      for (int j = 0; j < 3; ++j) {
        float s = __fadd_rn(__fadd_rn(__fmul_rn(R[i*3+0], inv[0*3+j]),
                                      __fmul_rn(R[i*3+1], inv[1*3+j])),
                            __fmul_rn(R[i*3+2], inv[2*3+j]));
        mats[bn * 9 + i * 3 + j] = s;
      }
  }
  {
    const float* A = post_rots + bn * 9;
    double a0=A[0],a1=A[1],a2=A[2],a3=A[3],a4=A[4],a5=A[5],a6=A[6],a7=A[7],a8=A[8];
    double det = a0*(a4*a8 - a5*a7) - a1*(a3*a8 - a5*a6) + a2*(a3*a7 - a4*a6);
    float* o = mats + 216 + bn * 9;
    o[0] = (float)((a4*a8 - a5*a7) / det);
    o[1] = (float)((a2*a7 - a1*a8) / det);
    o[2] = (float)((a1*a5 - a2*a4) / det);
    o[3] = (float)((a5*a6 - a3*a8) / det);
    o[4] = (float)((a0*a8 - a2*a6) / det);
    o[5] = (float)((a2*a3 - a0*a5) / det);
    o[6] = (float)((a3*a7 - a4*a6) / det);
    o[7] = (float)((a1*a6 - a0*a7) / det);
    o[8] = (float)((a0*a4 - a1*a3) / det);
  }
}

// ============ cam 3x3 conv 256->256 + relu, MFMA single-pass bf16 ============
// Ping-pong B: tap t+1's weights load to regs BEFORE tap t's MFMA (L2 latency
// hides under compute), ds_write after, ONE barrier per tap (was 2).
// Pad-44 keeps both A and B reads conflict-free. LDS 58.2 KB.
__global__ __launch_bounds__(256, 2) void cam_mfma(
    const u16* __restrict__ Gh,
    const u16* __restrict__ Wh,
    const float* __restrict__ bias, u16* __restrict__ Oh) {
  int nh = blockIdx.x;
  int n = nh >> 4, h = nh & 15;
  __shared__ u16 Ah[3 * 50 * 44];
  __shared__ u16 Bh[2][256 * 44];
  int tid = threadIdx.x;
  int wv = tid >> 6, l = tid & 63;
  int l15 = l & 15, kq = l >> 4;
  f32x4 acc[3][4] = {};
  const uint4 z4 = {0u, 0u, 0u, 0u};
  uint4 pb[4];
  auto loadB = [&](int cc, int t) {
    #pragma unroll
    for (int i = 0; i < 4; ++i) {
      int e = tid + i * 256;
      int q = e & 3, co = e >> 2;
      pb[i] = *(const uint4*)&Wh[((size_t)(t * 256 + co)) * 256 + cc * 32 + q * 8];
    }
  };
  auto writeB = [&](int p) {
    #pragma unroll
    for (int i = 0; i < 4; ++i) {
      int e = tid + i * 256;
      int q = e & 3, co = e >> 2;
      *(uint4*)&Bh[p][co * 44 + q * 8] = pb[i];
    }
  };
  for (int cc = 0; cc < 8; ++cc) {
    // previous tap-loop's final barrier protects Ah and Bh[0] reuse
    for (int e = tid; e < 600; e += 256) {
      int q = e & 3;
      int c = (e >> 2) % 50;
      int r = e / 200;
      int hh = h + r - 1, ww = c - 1;
      int off = (r * 50 + c) * 44 + q * 8;
      uint4 vh = z4;
      if (hh >= 0 && hh < FH && ww >= 0 && ww < FW) {
        size_t g = ((size_t)((n * FH + hh) * FW + ww)) * 256 + cc * 32 + q * 8;
        vh = *(const uint4*)&Gh[g];
      }
      *(uint4*)&Ah[off] = vh;
    }
    loadB(cc, 0);
    writeB(0);
    __syncthreads();
    for (int t = 0; t < 9; ++t) {
      if (t < 8) loadB(cc, t + 1);
      int ty = t / 3, tx = t % 3;
      const u16* Bcur = Bh[t & 1];
      bf16x8 bh[4];
      #pragma unroll
      for (int nf = 0; nf < 4; ++nf)
        bh[nf] = *(const bf16x8*)&Bcur[(wv * 64 + nf * 16 + l15) * 44 + kq * 8];
      #pragma unroll
      for (int mf = 0; mf < 3; ++mf) {
        int o = (ty * 50 + mf * 16 + l15 + tx) * 44 + kq * 8;
        bf16x8 ah = *(const bf16x8*)&Ah[o];
        #pragma unroll
        for (int nf = 0; nf < 4; ++nf)
          acc[mf][nf] = mfma16(ah, bh[nf], acc[mf][nf]);
      }
      if (t < 8) writeB((t + 1) & 1);
      __syncthreads();
    }
  }
  #pragma unroll
  for (int mf = 0; mf < 3; ++mf)
    #pragma unroll
    for (int nf = 0; nf < 4; ++nf) {
      int co = wv * 64 + nf * 16 + l15;
      float bv = bias[co];
      #pragma unroll
      for (int r = 0; r < 4; ++r) {
        int x = mf * 16 + kq * 4 + r;
        if (x < FW) {
          float v = fmaxf(acc[mf][nf][r] + bv, 0.f);
          size_t o = ((size_t)((n * FH + h) * FW + x)) * 256 + co;
          Oh[o] = f2bf_rne(v);
        }
      }
    }
}

// ============ BEV 3x3 conv CI->128 + relu, MFMA single-pass bf16 ============
// Ping-pong B (one barrier/tap, prefetch under MFMA). acc[4][8]=128 regs + 8
// prefetch ≈ 156 < the 170-reg cap of 3 waves/EU (round-9 lesson: never 4).
// A swizzle kq^((row>>1)&3); B pad 44. LDS 42.3 KB -> 3 blocks/CU.
template <int CI_>
__global__ __launch_bounds__(256, 3) void bev_mfma(
    const u16* __restrict__ Gh,
    const u16* __restrict__ Wh,
    const float* __restrict__ bias, u16* __restrict__ Oh) {
  int tile = blockIdx.x;
  int b = blockIdx.y;
  int y0 = (tile / 13) * 16, x0 = (tile % 13) * 16;
  __shared__ u16 Ah[18 * 18 * 32];
  __shared__ u16 Bh[2][128 * 44];
  int tid = threadIdx.x;
  int wv = tid >> 6, l = tid & 63;
  int l15 = l & 15, kq = l >> 4;
  f32x4 acc[4][8] = {};
  const uint4 z4 = {0u, 0u, 0u, 0u};
  uint4 pb[2];
  auto loadB = [&](int cc, int t) {
    #pragma unroll
    for (int i = 0; i < 2; ++i) {
      int e = tid + i * 256;
      int q = e & 3, co = e >> 2;
      pb[i] = *(const uint4*)&Wh[((size_t)(t * 128 + co)) * CI_ + cc * 32 + q * 8];
    }
  };
  auto writeB = [&](int p) {
    #pragma unroll
    for (int i = 0; i < 2; ++i) {
      int e = tid + i * 256;
      int q = e & 3, co = e >> 2;
      *(uint4*)&Bh[p][co * 44 + q * 8] = pb[i];
    }
  };
  for (int cc = 0; cc < CI_ / 32; ++cc) {
    for (int e = tid; e < 1296; e += 256) {
      int q = e & 3;
      int dx = (e >> 2) % 18;
      int dy = e / 72;
      int gy = y0 + dy - 1, gx = x0 + dx - 1;
      int row = dy * 18 + dx;
      int off = row * 32 + ((q ^ ((row >> 1) & 3)) * 8);
      uint4 vh = z4;
      if (gy >= 0 && gy < NX && gx >= 0 && gx < NX) {
        size_t g = ((size_t)((b * NX + gy) * NX + gx)) * CI_ + cc * 32 + q * 8;
        vh = *(const uint4*)&Gh[g];
      }
      *(uint4*)&Ah[off] = vh;
    }
    loadB(cc, 0);
    writeB(0);
    __syncthreads();
    for (int t = 0; t < 9; ++t) {
      if (t < 8) loadB(cc, t + 1);
      int ty = t / 3, tx = t % 3;
      const u16* Bcur = Bh[t & 1];
      bf16x8 bh[8];
      #pragma unroll
      for (int nf = 0; nf < 8; ++nf)
        bh[nf] = *(const bf16x8*)&Bcur[(nf * 16 + l15) * 44 + kq * 8];
      #pragma unroll
      for (int mf = 0; mf < 4; ++mf) {
        int row = (wv * 4 + mf + ty) * 18 + (l15 + tx);
        int o = row * 32 + ((kq ^ ((row >> 1) & 3)) * 8);
        bf16x8 ah = *(const bf16x8*)&Ah[o];
        #pragma unroll
        for (int nf = 0; nf < 8; ++nf)
          acc[mf][nf] = mfma16(ah, bh[nf], acc[mf][nf]);
      }
      if (t < 8) writeB((t + 1) & 1);
      __syncthreads();
    }
  }
  #pragma unroll
  for (int mf = 0; mf < 4; ++mf) {
    int y = y0 + wv * 4 + mf;
    if (y >= NX) continue;
    #pragma unroll
    for (int nf = 0; nf < 8; ++nf) {
      int co = nf * 16 + l15;
      float bv = bias[co];
      #pragma unroll
      for (int r = 0; r < 4; ++r) {
        int x = x0 + kq * 4 + r;
        if (x < NX) {
          float v = fmaxf(acc[mf][nf][r] + bv, 0.f);
          size_t o = ((size_t)((b * NX + y) * NX + x)) * 128 + co;
          Oh[o] = f2bf_rne(v);
        }
      }
    }
  }
}

// ============ cam 1x1 256->64 MFMA, single-pass bf16 ============
__global__ __launch_bounds__(256) void lin_mfma(const u16* __restrict__ Gh,
    const u16* __restrict__ Wh,
    const float* __restrict__ bias, float* __restrict__ out) {
  int wv = threadIdx.x >> 6, l = threadIdx.x & 63;
  int l15 = l & 15, kq = l >> 4;
  int pos0 = blockIdx.x * 256 + wv * 64;
  f32x4 acc[4][4] = {};
  for (int ks = 0; ks < 8; ++ks) {
    bf16x8 bh[4], ah[4];
    #pragma unroll
    for (int nf = 0; nf < 4; ++nf)
      bh[nf] = ld8(Wh + (nf * 16 + l15) * 256 + ks * 32 + kq * 8);
    #pragma unroll
    for (int mf = 0; mf < 4; ++mf)
      ah[mf] = ld8(Gh + ((size_t)(pos0 + mf * 16 + l15)) * 256 + ks * 32 + kq * 8);
    #pragma unroll
    for (int mf = 0; mf < 4; ++mf)
      #pragma unroll
      for (int nf = 0; nf < 4; ++nf)
        acc[mf][nf] = mfma16(ah[mf], bh[nf], acc[mf][nf]);
  }
  #pragma unroll
  for (int mf = 0; mf < 4; ++mf)
    #pragma unroll
    for (int nf = 0; nf < 4; ++nf) {
      float bv = bias[nf * 16 + l15];
      #pragma unroll
      for (int r = 0; r < 4; ++r) {
        int pos = pos0 + mf * 16 + kq * 4 + r;
        out[(size_t)pos * 64 + nf * 16 + l15] = acc[mf][nf][r] + bv;
      }
    }
}

// ============ dep 1x1 256->256 + relu MFMA (full 3-pass for softmax accuracy) ============
__global__ __launch_bounds__(256) void dep1_mfma(const u16* __restrict__ Gh,
    const u16* __restrict__ Gl, const u16* __restrict__ Wh, const u16* __restrict__ Wl,
    const float* __restrict__ bias, float* __restrict__ out) {
  int wv = threadIdx.x >> 6, l = threadIdx.x & 63;
  int l15 = l & 15, kq = l >> 4;
  int pos0 = blockIdx.x * 256 + wv * 64;
  int cog = blockIdx.y * 64;
  f32x4 acc[4][4] = {};
  for (int ks = 0; ks < 8; ++ks) {
    bf16x8 bh[4], bl[4], ah[4], al[4];
    #pragma unroll
    for (int nf = 0; nf < 4; ++nf) {
      int o = (cog + nf * 16 + l15) * 256 + ks * 32 + kq * 8;
      bh[nf] = ld8(Wh + o); bl[nf] = ld8(Wl + o);
    }
    #pragma unroll
    for (int mf = 0; mf < 4; ++mf) {
      size_t o = ((size_t)(pos0 + mf * 16 + l15)) * 256 + ks * 32 + kq * 8;
      ah[mf] = ld8(Gh + o); al[mf] = ld8(Gl + o);
    }
    #pragma unroll
    for (int mf = 0; mf < 4; ++mf)
      #pragma unroll
      for (int nf = 0; nf < 4; ++nf) {
        acc[mf][nf] = mfma16(ah[mf], bh[nf], acc[mf][nf]);
        acc[mf][nf] = mfma16(ah[mf], bl[nf], acc[mf][nf]);
        acc[mf][nf] = mfma16(al[mf], bh[nf], acc[mf][nf]);
      }
  }
  #pragma unroll
  for (int mf = 0; mf < 4; ++mf)
    #pragma unroll
    for (int nf = 0; nf < 4; ++nf) {
      int co = cog + nf * 16 + l15;
      float bv = bias[co];
      #pragma unroll
      for (int r = 0; r < 4; ++r) {
        int pos = pos0 + mf * 16 + kq * 4 + r;
        out[(size_t)pos * 256 + co] = fmaxf(acc[mf][nf][r] + bv, 0.f);
      }
    }
}

// ============ fus 1x1 64->64 MFMA (bev0 f32 split in-reg, bf16 out plane) ============
__global__ __launch_bounds__(256) void fus_mfma(const float* __restrict__ in,
    const u16* __restrict__ Wh, const u16* __restrict__ Wl,
    const float* __restrict__ bias, u16* __restrict__ oh) {
  int wv = threadIdx.x >> 6, l = threadIdx.x & 63;
  int l15 = l & 15, kq = l >> 4;
  int pos0 = blockIdx.x * 256 + wv * 64;
  f32x4 acc[4][4] = {};
  for (int ks = 0; ks < 2; ++ks) {
    bf16x8 bh[4], bl[4], ah[4], al[4];
    #pragma unroll
    for (int nf = 0; nf < 4; ++nf) {
      int o = (nf * 16 + l15) * 64 + ks * 32 + kq * 8;
      bh[nf] = ld8(Wh + o); bl[nf] = ld8(Wl + o);
    }
    #pragma unroll
    for (int mf = 0; mf < 4; ++mf) {
      size_t o = ((size_t)(pos0 + mf * 16 + l15)) * 64 + ks * 32 + kq * 8;
      float4 v0 = *(const float4*)&in[o];
      float4 v1 = *(const float4*)&in[o + 4];
      float xs[8] = {v0.x, v0.y, v0.z, v0.w, v1.x, v1.y, v1.z, v1.w};
      u16 th[8], tl[8];
      #pragma unroll
      for (int i = 0; i < 8; ++i) split_bf(xs[i], th[i], tl[i]);
      ah[mf] = *(const bf16x8*)th;
      al[mf] = *(const bf16x8*)tl;
    }
    #pragma unroll
    for (int mf = 0; mf < 4; ++mf)
      #pragma unroll
      for (int nf = 0; nf < 4; ++nf) {
        acc[mf][nf] = mfma16(ah[mf], bh[nf], acc[mf][nf]);
        acc[mf][nf] = mfma16(ah[mf], bl[nf], acc[mf][nf]);
        acc[mf][nf] = mfma16(al[mf], bh[nf], acc[mf][nf]);
      }
  }
  #pragma unroll
  for (int mf = 0; mf < 4; ++mf)
    #pragma unroll
    for (int nf = 0; nf < 4; ++nf) {
      int c = nf * 16 + l15;
      float bv = bias[c];
      #pragma unroll
      for (int r = 0; r < 4; ++r) {
        int pos = pos0 + mf * 16 + kq * 4 + r;
        oh[(size_t)pos * 64 + c] = f2bf_rne(acc[mf][nf][r] + bv);
      }
    }
}

// ============ out 1x1 128->64 MFMA (split weights, bf16 acts) ============
__global__ __launch_bounds__(256) void out_mfma(const u16* __restrict__ Wh,
    const u16* __restrict__ Wl, const u16* __restrict__ Gh,
    const float* __restrict__ bias, float* __restrict__ out) {
  int wv = threadIdx.x >> 6, l = threadIdx.x & 63;
  int l15 = l & 15, kq = l >> 4;
  int pos0 = blockIdx.x * 256 + wv * 64;
  f32x4 acc[4][4] = {};
  for (int ks = 0; ks < 4; ++ks) {
    bf16x8 ah[4], al[4], bh[4];
    #pragma unroll
    for (int mf = 0; mf < 4; ++mf) {
      int o = (mf * 16 + l15) * 128 + ks * 32 + kq * 8;
      ah[mf] = ld8(Wh + o); al[mf] = ld8(Wl + o);
    }
    #pragma unroll
    for (int nf = 0; nf < 4; ++nf)
      bh[nf] = ld8(Gh + ((size_t)(pos0 + nf * 16 + l15)) * 128 + ks * 32 + kq * 8);
    #pragma unroll
    for (int mf = 0; mf < 4; ++mf)
      #pragma unroll
      for (int nf = 0; nf < 4; ++nf) {
        acc[mf][nf] = mfma16(ah[mf], bh[nf], acc[mf][nf]);
        acc[mf][nf] = mfma16(al[mf], bh[nf], acc[mf][nf]);
      }
  }
  #pragma unroll
  for (int mf = 0; mf < 4; ++mf)
    #pragma unroll
    for (int r = 0; r < 4; ++r) {
      int co = mf * 16 + kq * 4 + r;
      float bv = bias[co];
      #pragma unroll
      for (int nf = 0; nf < 4; ++nf) {
        int pos = pos0 + nf * 16 + l15;
        int b = pos / 40000;
        int xy = pos - b * 40000;
        out[((size_t)(b * CC + co)) * 40000 + xy] = acc[mf][nf][r] + bv;
      }
    }
}

// ============ depth 1x1 conv 256->41 + softmax ============
__global__ __launch_bounds__(256) void dep_softmax(const float* __restrict__ in,
    const float* __restrict__ wt, const float* __restrict__ bias, float* __restrict__ depth) {
  int nh = blockIdx.x;
  int n = nh >> 4, h = nh & 15;
  __shared__ float lds[256][49];
  __shared__ float lg[ND][FW];
  int tid = threadIdx.x;
  for (int e = tid; e < 256 * 48; e += 256) {
    int ci = e % 256, w = e / 256;
    lds[ci][w] = (w < FW) ? in[((size_t)((n * FH + h) * FW + w)) * 256 + ci] : 0.f;
  }
  __syncthreads();
  int co = tid >> 2, wseg = tid & 3;
  int ob = wseg * 12;
  int nj = (wseg == 3) ? 8 : 12;
  if (co < ND) {
    float acc[12];
    #pragma unroll
    for (int j = 0; j < 12; ++j) acc[j] = 0.f;
    const float* wp = wt + co * 256;
    for (int ci = 0; ci < 256; ++ci) {
      float wv = wp[ci];
      #pragma unroll
      for (int j = 0; j < 12; ++j) acc[j] += wv * lds[ci][ob + j];
    }
    float b = bias[co];
    for (int j = 0; j < nj; ++j) lg[co][ob + j] = acc[j] + b;
  }
  __syncthreads();
  if (tid < FW) {
    int w = tid;
    float m = lg[0][w];
    #pragma unroll
    for (int d = 1; d < ND; ++d) m = fmaxf(m, lg[d][w]);
    float s = 0.f;
    #pragma unroll
    for (int d = 0; d < ND; ++d) s += expf(lg[d][w] - m);
    #pragma unroll
    for (int d = 0; d < ND; ++d)
      depth[((n * ND + d) * FH + h) * FW + w] = expf(lg[d][w] - m) / s;
  }
}

// ============ splat: one wave per (bn,d,w) ray group; run-length cell flush ============
__global__ __launch_bounds__(256) void splat(const float* __restrict__ depth,
    const float* __restrict__ img, const float* __restrict__ mats,
    const float* __restrict__ trans, const float* __restrict__ ptrans,
    float* __restrict__ bev0) {
  int gid = blockIdx.x * 4 + (threadIdx.x >> 6);
  int c = threadIdx.x & 63;
  int w = gid % FW;
  int t = gid / FW;
  int d = t % ND;
  int bn = t / ND;
  int b = bn / NCAM;
  float fx = (w == FW - 1) ? 703.0f : (float)((double)w * (703.0 / 43.0));
  float fz = (float)(4 + d);
  const float* pt = ptrans + bn * 3;
  const float* P = mats + 216 + bn * 9;
  const float* M = mats + bn * 9;
  const float* tr = trans + bn * 3;
  float px = __fsub_rn(fx, pt[0]);
  float pz = __fsub_rn(fz, pt[2]);
  const float* dp = depth + ((size_t)(bn * ND + d) * FH) * FW + w;
  const float* ip = img + ((size_t)(bn * FH) * FW + w) * CC + c;
  int cell = -1;
  float acc = 0.f;
  for (int h = 0; h < FH; ++h) {
    float fy = (float)(17 * h);
    float py = __fsub_rn(fy, pt[1]);
    float q0 = __fadd_rn(__fadd_rn(__fmul_rn(P[0], px), __fmul_rn(P[1], py)), __fmul_rn(P[2], pz));
    float q1 = __fadd_rn(__fadd_rn(__fmul_rn(P[3], px), __fmul_rn(P[4], py)), __fmul_rn(P[5], pz));
    float q2 = __fadd_rn(__fadd_rn(__fmul_rn(P[6], px), __fmul_rn(P[7], py)), __fmul_rn(P[8], pz));
    float r0 = __fmul_rn(q0, q2), r1 = __fmul_rn(q1, q2), r2 = q2;
    float u0 = __fadd_rn(__fadd_rn(__fadd_rn(__fmul_rn(M[0], r0), __fmul_rn(M[1], r1)), __fmul_rn(M[2], r2)), tr[0]);
    float u1 = __fadd_rn(__fadd_rn(__fadd_rn(__fmul_rn(M[3], r0), __fmul_rn(M[4], r1)), __fmul_rn(M[5], r2)), tr[1]);
    float u2 = __fadd_rn(__fadd_rn(__fadd_rn(__fmul_rn(M[6], r0), __fmul_rn(M[7], r1)), __fmul_rn(M[8], r2)), tr[2]);
    int gx = (int)__fmul_rn(__fadd_rn(u0, 50.0f), 2.0f);
    int gy = (int)__fmul_rn(__fadd_rn(u1, 50.0f), 2.0f);
    int gz = (int)__fdiv_rn(__fadd_rn(u2, 10.0f), 20.0f);
    bool kept = (gx >= 0 && gx < NX && gy >= 0 && gy < NX && gz == 0);
    int c2 = kept ? (b * NX + gx) * NX + gy : -1;
    if (c2 != cell) {
      if (cell >= 0) atomicAdd(&bev0[(size_t)cell * CC + c], acc);
      cell = c2;
      acc = 0.f;
    }
    if (kept)
      acc = __fadd_rn(acc, __fmul_rn(dp[h * FW], ip[(size_t)h * FW * CC]));
  }
  if (cell >= 0) atomicAdd(&bev0[(size_t)cell * CC + c], acc);
}

extern "C" void kernel_launch(void* const* d_in, const int* in_sizes, int n_in,
                              void* d_out, int out_size, void* d_ws, size_t ws_size,
                              hipStream_t stream) {
  const float* feat       = (const float*)d_in[0];
  const float* rots       = (const float*)d_in[1];
  const float* trans      = (const float*)d_in[2];
  const float* intrins    = (const float*)d_in[3];
  const float* post_trans = (const float*)d_in[5];
  const float* post_rots  = (const float*)d_in[6];
  const float* cam_w1 = (const float*)d_in[7];
  const float* cam_b1 = (const float*)d_in[8];
  const float* cam_w2 = (const float*)d_in[9];
  const float* cam_b2 = (const float*)d_in[10];
  const float* cam_wl = (const float*)d_in[11];
  const float* cam_bl = (const float*)d_in[12];
  const float* dep_w1 = (const float*)d_in[13];
  const float* dep_b1 = (const float*)d_in[14];
  const float* dep_wl = (const float*)d_in[15];
  const float* dep_bl = (const float*)d_in[16];
  const float* fus_w  = (const float*)d_in[17];
  const float* fus_b  = (const float*)d_in[18];
  const float* bev_w1 = (const float*)d_in[19];
  const float* bev_b1 = (const float*)d_in[20];
  const float* bev_w2 = (const float*)d_in[21];
  const float* bev_b2 = (const float*)d_in[22];
  const float* bev_wl = (const float*)d_in[23];
  const float* bev_bl = (const float*)d_in[24];

  char* wsb = (char*)d_ws;
  u16* featT_h = (u16*)(wsb + WS_FEATT_HI);
  u16* featT_l = (u16*)(wsb + WS_FEATT_LO);
  u16* h1_h = (u16*)(wsb + WS_H1_HI);
  u16* h2_h = (u16*)(wsb + WS_H2_HI);
  float* h1d = (float*)(wsb + WS_H1D);
  u16* bw1_h = (u16*)(wsb + WS_BW1_HI);
  u16* bw1_l = (u16*)(wsb + WS_BW1_LO);
  float* bev0 = (float*)(wsb + WS_BEV0);
  u16* cw1_h = (u16*)(wsb + WS_CW1_HI);
  u16* cw1_l = (u16*)(wsb + WS_CW1_LO);
  u16* cw2_h = (u16*)(wsb + WS_CW2_HI);
  u16* cw2_l = (u16*)(wsb + WS_CW2_LO);
  u16* cwl_h = (u16*)(wsb + WS_CWL_HI);
  u16* cwl_l = (u16*)(wsb + WS_CWL_LO);
  u16* dw1_h = (u16*)(wsb + WS_DW1_HI);
  u16* dw1_l = (u16*)(wsb + WS_DW1_LO);
  float* dep  = (float*)(wsb + WS_DEP);
  float* imgt = (float*)(wsb + WS_IMGT);
  float* mats = (float*)(wsb + WS_MATS);
  u16* fusw_h = (u16*)(wsb + WS_FUSW_HI);
  u16* fusw_l = (u16*)(wsb + WS_FUSW_LO);
  u16* bev1_h = (u16*)(wsb + WS_BEV1_HI);
  u16* hb1_h = (u16*)(wsb + WS_HB1_HI);
  u16* hb2_h = (u16*)(wsb + WS_HB2_HI);
  u16* bw2_h = (u16*)(wsb + WS_BW2_HI);
  u16* bw2_l = (u16*)(wsb + WS_BW2_LO);
  u16* bwl_h = (u16*)(wsb + WS_BWL_HI);
  u16* bwl_l = (u16*)(wsb + WS_BWL_LO);

  // prep
  featsplit<<<NBN * FH, 256, 0, stream>>>(feat, featT_h, featT_l);
  wsplit3<<<2304, 256, 0, stream>>>(cam_w1, cw1_h, cw1_l, 256, 256);
  wsplit3<<<2304, 256, 0, stream>>>(cam_w2, cw2_h, cw2_l, 256, 256);
  wsplit3<<<288, 256, 0, stream>>>(bev_w1, bw1_h, bw1_l, 128, 64);
  wsplit3<<<576, 256, 0, stream>>>(bev_w2, bw2_h, bw2_l, 128, 128);
  wsplit1<<<64, 256, 0, stream>>>(cam_wl, cwl_h, cwl_l, 64 * 256);
  wsplit1<<<256, 256, 0, stream>>>(dep_w1, dw1_h, dw1_l, 256 * 256);
  wsplit1<<<32, 256, 0, stream>>>(bev_wl, bwl_h, bwl_l, 64 * 128);
  wsplit1<<<16, 256, 0, stream>>>(fus_w, fusw_h, fusw_l, 64 * 64);
  prep_mats<<<1, 32, 0, stream>>>(rots, intrins, post_rots, mats);

  // cam encoder (MFMA, single-pass bf16, ping-pong B)
  cam_mfma<<<NBN * FH, 256, 0, stream>>>(featT_h, cw1_h, cam_b1, h1_h);
  cam_mfma<<<NBN * FH, 256, 0, stream>>>(h1_h, cw2_h, cam_b2, h2_h);
  lin_mfma<<<66, 256, 0, stream>>>(h2_h, cwl_h, cam_bl, imgt);

  // depth head (MFMA from featT planes, full 3-pass for softmax accuracy)
  dep1_mfma<<<dim3(66, 4), 256, 0, stream>>>(featT_h, featT_l, dw1_h, dw1_l, dep_b1, h1d);
  dep_softmax<<<NBN * FH, 256, 0, stream>>>(h1d, dep_wl, dep_bl, dep);

  // splat (ray-grouped)
  hipMemsetAsync((void*)bev0, 0, 40960000ul, stream);
  splat<<<(NBN * ND * FW) / 4, 256, 0, stream>>>(dep, imgt, mats, trans, post_trans, bev0);

  // fusion + BEV encoder (MFMA, single-pass bf16 convs, ping-pong B)
  fus_mfma<<<625, 256, 0, stream>>>(bev0, fusw_h, fusw_l, fus_b, bev1_h);
  bev_mfma<64><<<dim3(169, NB), 256, 0, stream>>>(bev1_h, bw1_h, bev_b1, hb1_h);
  bev_mfma<128><<<dim3(169, NB), 256, 0, stream>>>(hb1_h, bw2_h, bev_b2, hb2_h);
  out_mfma<<<625, 256, 0, stream>>>(bwl_h, bwl_l, hb2_h, bev_bl, (float*)d_out);
}

// Round 12
// 580.888 us; speedup vs baseline: 1.6547x; 1.6547x over previous
//
#include <hip/hip_runtime.h>
#include <hip/hip_bf16.h>

typedef unsigned short u16;
typedef __bf16 bf16x8 __attribute__((ext_vector_type(8)));
typedef float f32x4 __attribute__((ext_vector_type(4)));

#define NB 4
#define NCAM 6
#define NBN 24
#define CIN 256
#define CC 64
#define ND 41
#define FH 16
#define FW 44
#define NX 200

// ---- workspace byte offsets (overlaid; max used 164,462,592 B) ----
#define WS_FEATT_HI 0ul
#define WS_FEATT_LO 8650752ul
#define WS_H1_HI    17301504ul
#define WS_H2_HI    34603008ul
#define WS_H1D      51904512ul
#define WS_BW1_HI   69206016ul
#define WS_BW1_LO   69353472ul
#define WS_BEV0     76302336ul
#define WS_CW1_HI   117262336ul
#define WS_CW1_LO   118441984ul
#define WS_CW2_HI   119621632ul
#define WS_CW2_LO   120801280ul
#define WS_CWL_HI   121980928ul
#define WS_CWL_LO   122013696ul
#define WS_DW1_HI   122046464ul
#define WS_DW1_LO   122177536ul
#define WS_DEP      122308608ul
#define WS_IMGT     125079552ul
#define WS_MATS     129404928ul
#define WS_FUSW_HI  129406656ul
#define WS_FUSW_LO  129414848ul
#define WS_BEV1_HI  0ul            // u16 [4*200*200*64]; fus->bev<64>; cam bufs dead
#define WS_HB1_HI   81920000ul     // u16 [4*200*200*128]; bev<64>->bev<128>
#define WS_HB2_HI   0ul            // u16 [4*200*200*128]; bev<128>->out (bev1 dead)
#define WS_BW2_HI   163840000ul
#define WS_BW2_LO   164134912ul
#define WS_BWL_HI   164429824ul
#define WS_BWL_LO   164446208ul

__device__ inline u16 f2bf_rne(float x) {
  unsigned u = __float_as_uint(x);
  unsigned r = u + 0x7fffu + ((u >> 16) & 1u);
  return (u16)(r >> 16);
}
__device__ inline float bf2f(u16 h) { return __uint_as_float(((unsigned)h) << 16); }
__device__ inline void split_bf(float x, u16& hi, u16& lo) {
  hi = f2bf_rne(x);
  lo = f2bf_rne(x - bf2f(hi));
}
__device__ inline f32x4 mfma16(bf16x8 a, bf16x8 b, f32x4 c) {
  return __builtin_amdgcn_mfma_f32_16x16x32_bf16(a, b, c, 0, 0, 0);
}
__device__ inline bf16x8 ld8(const u16* p) { return *(const bf16x8*)p; }

// ============ feat NCHW f32 -> NHWC hi/lo planes ============
__global__ __launch_bounds__(256) void featsplit(const float* __restrict__ in,
    u16* __restrict__ oh, u16* __restrict__ ol) {
  int nh = blockIdx.x;
  int n = nh >> 4, h = nh & 15;
  __shared__ float lds[256][44];
  int tid = threadIdx.x;
  for (int e = tid; e < 256 * 44; e += 256) {
    int ci = e / 44, w = e % 44;
    lds[ci][w] = in[((n * CIN + ci) * FH + h) * FW + w];
  }
  __syncthreads();
  for (int e = tid; e < 256 * 44; e += 256) {
    int w = e / 256, ci = e % 256;
    u16 hi, lo;
    split_bf(lds[ci][w], hi, lo);
    size_t o = ((size_t)((n * FH + h) * FW + w)) * 256 + ci;
    oh[o] = hi; ol[o] = lo;
  }
}

// ============ weight split 3x3 ============
__global__ __launch_bounds__(256) void wsplit3(const float* __restrict__ src,
    u16* __restrict__ dhi, u16* __restrict__ dlo, int CO, int CI_) {
  int idx = blockIdx.x * 256 + threadIdx.x;
  if (idx >= CO * CI_ * 9) return;
  int co = idx / (CI_ * 9);
  int r = idx % (CI_ * 9);
  int ci = r / 9, t = r % 9;
  u16 h, l;
  split_bf(src[idx], h, l);
  int o = (t * CO + co) * CI_ + ci;
  dhi[o] = h; dlo[o] = l;
}

// ============ weight split 1x1 ============
__global__ __launch_bounds__(256) void wsplit1(const float* __restrict__ src,
    u16* __restrict__ dhi, u16* __restrict__ dlo, int n) {
  int i = blockIdx.x * 256 + threadIdx.x;
  if (i >= n) return;
  u16 h, l;
  split_bf(src[i], h, l);
  dhi[i] = h; dlo[i] = l;
}

// ============ per-(b,n) matrices ============
__global__ void prep_mats(const float* __restrict__ rots, const float* __restrict__ intrins,
                          const float* __restrict__ post_rots, float* __restrict__ mats) {
  int bn = threadIdx.x;
  if (bn >= NBN) return;
  {
    const float* A = intrins + bn * 9;
    double a0=A[0],a1=A[1],a2=A[2],a3=A[3],a4=A[4],a5=A[5],a6=A[6],a7=A[7],a8=A[8];
    double det = a0*(a4*a8 - a5*a7) - a1*(a3*a8 - a5*a6) + a2*(a3*a7 - a4*a6);
    float inv[9];
    inv[0] = (float)((a4*a8 - a5*a7) / det);
    inv[1] = (float)((a2*a7 - a1*a8) / det);
    inv[2] = (float)((a1*a5 - a2*a4) / det);
    inv[3] = (float)((a5*a6 - a3*a8) / det);
    inv[4] = (float)((a0*a8 - a2*a6) / det);
    inv[5] = (float)((a2*a3 - a0*a5) / det);
    inv[6] = (float)((a3*a7 - a4*a6) / det);
    inv[7] = (float)((a1*a6 - a0*a7) / det);
    inv[8] = (float)((a0*a4 - a1*a3) / det);
    const float* R = rots + bn * 9;
    #pragma unroll
    for (int i = 0; i < 3; ++i)
      #pragma unroll
      for (int j = 0; j < 3; ++j) {
        float s = __fadd_rn(__fadd_rn(__fmul_rn(R[i*3+0], inv[0*3+j]),
                                      __fmul_rn(R[i*3+1], inv[1*3+j])),
                            __fmul_rn(R[i*3+2], inv[2*3+j]));
        mats[bn * 9 + i * 3 + j] = s;
      }
  }
  {
    const float* A = post_rots + bn * 9;
    double a0=A[0],a1=A[1],a2=A[2],a3=A[3],a4=A[4],a5=A[5],a6=A[6],a7=A[7],a8=A[8];
    double det = a0*(a4*a8 - a5*a7) - a1*(a3*a8 - a5*a6) + a2*(a3*a7 - a4*a6);
    float* o = mats + 216 + bn * 9;
    o[0] = (float)((a4*a8 - a5*a7) / det);
    o[1] = (float)((a2*a7 - a1*a8) / det);
    o[2] = (float)((a1*a5 - a2*a4) / det);
    o[3] = (float)((a5*a6 - a3*a8) / det);
    o[4] = (float)((a0*a8 - a2*a6) / det);
    o[5] = (float)((a2*a3 - a0*a5) / det);
    o[6] = (float)((a3*a7 - a4*a6) / det);
    o[7] = (float)((a1*a6 - a0*a7) / det);
    o[8] = (float)((a0*a4 - a1*a3) / det);
  }
}

// ============ cam 3x3 conv 256->256 + relu, MFMA single-pass bf16 ============
// Round-10 proven loop. Epilogue: transpose acc through Bh (dead after K-loop)
// and store coalesced uint4 (was per-lane 2B scattered stores -> 2.8x WRITE ampl).
__global__ __launch_bounds__(256, 4) void cam_mfma(
    const u16* __restrict__ Gh,
    const u16* __restrict__ Wh,
    const float* __restrict__ bias, u16* __restrict__ Oh) {
  int nh = blockIdx.x;
  int n = nh >> 4, h = nh & 15;
  __shared__ u16 Ah[3 * 50 * 44];
  __shared__ u16 Bh[256 * 44];
  int tid = threadIdx.x;
  int wv = tid >> 6, l = tid & 63;
  int l15 = l & 15, kq = l >> 4;
  f32x4 acc[3][4] = {};
  const uint4 z4 = {0u, 0u, 0u, 0u};
  for (int cc = 0; cc < 8; ++cc) {
    __syncthreads();
    for (int e = tid; e < 600; e += 256) {
      int q = e & 3;
      int c = (e >> 2) % 50;
      int r = e / 200;
      int hh = h + r - 1, ww = c - 1;
      int off = (r * 50 + c) * 44 + q * 8;
      uint4 vh = z4;
      if (hh >= 0 && hh < FH && ww >= 0 && ww < FW) {
        size_t g = ((size_t)((n * FH + hh) * FW + ww)) * 256 + cc * 32 + q * 8;
        vh = *(const uint4*)&Gh[g];
      }
      *(uint4*)&Ah[off] = vh;
    }
    for (int t = 0; t < 9; ++t) {
      __syncthreads();
      for (int e = tid; e < 1024; e += 256) {
        int q = e & 3;
        int co = e >> 2;
        size_t g = ((size_t)(t * 256 + co)) * 256 + cc * 32 + q * 8;
        *(uint4*)&Bh[co * 44 + q * 8] = *(const uint4*)&Wh[g];
      }
      __syncthreads();
      int ty = t / 3, tx = t % 3;
      bf16x8 bh[4];
      #pragma unroll
      for (int nf = 0; nf < 4; ++nf)
        bh[nf] = *(const bf16x8*)&Bh[(wv * 64 + nf * 16 + l15) * 44 + kq * 8];
      #pragma unroll
      for (int mf = 0; mf < 3; ++mf) {
        int o = (ty * 50 + mf * 16 + l15 + tx) * 44 + kq * 8;
        bf16x8 ah = *(const bf16x8*)&Ah[o];
        #pragma unroll
        for (int nf = 0; nf < 4; ++nf)
          acc[mf][nf] = mfma16(ah, bh[nf], acc[mf][nf]);
      }
    }
  }
  // --- coalesced store epilogue via Bh transpose buffer (44*256 u16 = fits exactly) ---
  __syncthreads();
  #pragma unroll
  for (int mf = 0; mf < 3; ++mf)
    #pragma unroll
    for (int nf = 0; nf < 4; ++nf) {
      int co = wv * 64 + nf * 16 + l15;
      float bv = bias[co];
      #pragma unroll
      for (int r = 0; r < 4; ++r) {
        int x = mf * 16 + kq * 4 + r;
        if (x < FW)
          Bh[x * 256 + co] = f2bf_rne(fmaxf(acc[mf][nf][r] + bv, 0.f));
      }
    }
  __syncthreads();
  for (int uid = tid; uid < FW * 32; uid += 256) {
    int x = uid >> 5, c16 = uid & 31;
    *(uint4*)&Oh[(((size_t)((n * FH + h) * FW + x)) * 256) + c16 * 8] =
        *(const uint4*)&Bh[x * 256 + c16 * 8];
  }
}

// ============ BEV 3x3 conv CI->128 + relu, MFMA single-pass bf16 ============
// Round-10 proven loop (2 barriers/tap, LDS B — rounds 5/7/9/11 all proved
// alternatives spill or stall). acc[4][8]=128 regs: 3 waves/EU, never more.
// Epilogue: per-mf transpose through Ah -> coalesced uint4 stores.
template <int CI_>
__global__ __launch_bounds__(256, 3) void bev_mfma(
    const u16* __restrict__ Gh,
    const u16* __restrict__ Wh,
    const float* __restrict__ bias, u16* __restrict__ Oh) {
  int tile = blockIdx.x;
  int b = blockIdx.y;
  int y0 = (tile / 13) * 16, x0 = (tile % 13) * 16;
  __shared__ u16 Ah[18 * 18 * 32];
  __shared__ u16 Bh[128 * 44];
  int tid = threadIdx.x;
  int wv = tid >> 6, l = tid & 63;
  int l15 = l & 15, kq = l >> 4;
  f32x4 acc[4][8] = {};
  const uint4 z4 = {0u, 0u, 0u, 0u};
  for (int cc = 0; cc < CI_ / 32; ++cc) {
    __syncthreads();
    for (int e = tid; e < 1296; e += 256) {
      int q = e & 3;
      int dx = (e >> 2) % 18;
      int dy = e / 72;
      int gy = y0 + dy - 1, gx = x0 + dx - 1;
      int row = dy * 18 + dx;
      int off = row * 32 + ((q ^ ((row >> 1) & 3)) * 8);
      uint4 vh = z4;
      if (gy >= 0 && gy < NX && gx >= 0 && gx < NX) {
        size_t g = ((size_t)((b * NX + gy) * NX + gx)) * CI_ + cc * 32 + q * 8;
        vh = *(const uint4*)&Gh[g];
      }
      *(uint4*)&Ah[off] = vh;
    }
    for (int t = 0; t < 9; ++t) {
      __syncthreads();
      for (int e = tid; e < 512; e += 256) {
        int q = e & 3;
        int co = e >> 2;
        size_t g = ((size_t)(t * 128 + co)) * CI_ + cc * 32 + q * 8;
        *(uint4*)&Bh[co * 44 + q * 8] = *(const uint4*)&Wh[g];
      }
      __syncthreads();
      int ty = t / 3, tx = t % 3;
      bf16x8 bh[8];
      #pragma unroll
      for (int nf = 0; nf < 8; ++nf)
        bh[nf] = *(const bf16x8*)&Bh[(nf * 16 + l15) * 44 + kq * 8];
      #pragma unroll
      for (int mf = 0; mf < 4; ++mf) {
        int row = (wv * 4 + mf + ty) * 18 + (l15 + tx);
        int o = row * 32 + ((kq ^ ((row >> 1) & 3)) * 8);
        bf16x8 ah = *(const bf16x8*)&Ah[o];
        #pragma unroll
        for (int nf = 0; nf < 8; ++nf)
          acc[mf][nf] = mfma16(ah, bh[nf], acc[mf][nf]);
      }
    }
  }
  // --- coalesced store epilogue: per-mf slice through Ah (8192 u16 <= 10368) ---
  u16* st = Ah;
  for (int mf = 0; mf < 4; ++mf) {
    __syncthreads();
    #pragma unroll
    for (int nf = 0; nf < 8; ++nf) {
      int co = nf * 16 + l15;
      float bv = bias[co];
      #pragma unroll
      for (int r = 0; r < 4; ++r) {
        int xx = kq * 4 + r;
        st[(wv * 16 + xx) * 128 + co] = f2bf_rne(fmaxf(acc[mf][nf][r] + bv, 0.f));
      }
    }
    __syncthreads();
    #pragma unroll
    for (int k = 0; k < 4; ++k) {
      int uid = tid + k * 256;
      int pos = uid >> 4, c16 = uid & 15;
      int wvp = pos >> 4, xx = pos & 15;
      int yy = y0 + wvp * 4 + mf, gx = x0 + xx;
      if (yy < NX && gx < NX)
        *(uint4*)&Oh[(((size_t)(b * NX + yy)) * NX + gx) * 128 + c16 * 8] =
            *(const uint4*)&st[pos * 128 + c16 * 8];
    }
  }
}

// ============ cam 1x1 256->64 MFMA, single-pass bf16 ============
__global__ __launch_bounds__(256) void lin_mfma(const u16* __restrict__ Gh,
    const u16* __restrict__ Wh,
    const float* __restrict__ bias, float* __restrict__ out) {
  int wv = threadIdx.x >> 6, l = threadIdx.x & 63;
  int l15 = l & 15, kq = l >> 4;
  int pos0 = blockIdx.x * 256 + wv * 64;
  f32x4 acc[4][4] = {};
  for (int ks = 0; ks < 8; ++ks) {
    bf16x8 bh[4], ah[4];
    #pragma unroll
    for (int nf = 0; nf < 4; ++nf)
      bh[nf] = ld8(Wh + (nf * 16 + l15) * 256 + ks * 32 + kq * 8);
    #pragma unroll
    for (int mf = 0; mf < 4; ++mf)
      ah[mf] = ld8(Gh + ((size_t)(pos0 + mf * 16 + l15)) * 256 + ks * 32 + kq * 8);
    #pragma unroll
    for (int mf = 0; mf < 4; ++mf)
      #pragma unroll
      for (int nf = 0; nf < 4; ++nf)
        acc[mf][nf] = mfma16(ah[mf], bh[nf], acc[mf][nf]);
  }
  #pragma unroll
  for (int mf = 0; mf < 4; ++mf)
    #pragma unroll
    for (int nf = 0; nf < 4; ++nf) {
      float bv = bias[nf * 16 + l15];
      #pragma unroll
      for (int r = 0; r < 4; ++r) {
        int pos = pos0 + mf * 16 + kq * 4 + r;
        out[(size_t)pos * 64 + nf * 16 + l15] = acc[mf][nf][r] + bv;
      }
    }
}

// ============ dep 1x1 256->256 + relu MFMA (full 3-pass for softmax accuracy) ============
__global__ __launch_bounds__(256) void dep1_mfma(const u16* __restrict__ Gh,
    const u16* __restrict__ Gl, const u16* __restrict__ Wh, const u16* __restrict__ Wl,
    const float* __restrict__ bias, float* __restrict__ out) {
  int wv = threadIdx.x >> 6, l = threadIdx.x & 63;
  int l15 = l & 15, kq = l >> 4;
  int pos0 = blockIdx.x * 256 + wv * 64;
  int cog = blockIdx.y * 64;
  f32x4 acc[4][4] = {};
  for (int ks = 0; ks < 8; ++ks) {
    bf16x8 bh[4], bl[4], ah[4], al[4];
    #pragma unroll
    for (int nf = 0; nf < 4; ++nf) {
      int o = (cog + nf * 16 + l15) * 256 + ks * 32 + kq * 8;
      bh[nf] = ld8(Wh + o); bl[nf] = ld8(Wl + o);
    }
    #pragma unroll
    for (int mf = 0; mf < 4; ++mf) {
      size_t o = ((size_t)(pos0 + mf * 16 + l15)) * 256 + ks * 32 + kq * 8;
      ah[mf] = ld8(Gh + o); al[mf] = ld8(Gl + o);
    }
    #pragma unroll
    for (int mf = 0; mf < 4; ++mf)
      #pragma unroll
      for (int nf = 0; nf < 4; ++nf) {
        acc[mf][nf] = mfma16(ah[mf], bh[nf], acc[mf][nf]);
        acc[mf][nf] = mfma16(ah[mf], bl[nf], acc[mf][nf]);
        acc[mf][nf] = mfma16(al[mf], bh[nf], acc[mf][nf]);
      }
  }
  #pragma unroll
  for (int mf = 0; mf < 4; ++mf)
    #pragma unroll
    for (int nf = 0; nf < 4; ++nf) {
      int co = cog + nf * 16 + l15;
      float bv = bias[co];
      #pragma unroll
      for (int r = 0; r < 4; ++r) {
        int pos = pos0 + mf * 16 + kq * 4 + r;
        out[(size_t)pos * 256 + co] = fmaxf(acc[mf][nf][r] + bv, 0.f);
      }
    }
}

// ============ fus 1x1 64->64 MFMA (bev0 f32 split in-reg, bf16 out plane) ============
__global__ __launch_bounds__(256) void fus_mfma(const float* __restrict__ in,
    const u16* __restrict__ Wh, const u16* __restrict__ Wl,
    const float* __restrict__ bias, u16* __restrict__ oh) {
  int wv = threadIdx.x >> 6, l = threadIdx.x & 63;
  int l15 = l & 15, kq = l >> 4;
  int pos0 = blockIdx.x * 256 + wv * 64;
  f32x4 acc[4][4] = {};
  for (int ks = 0; ks < 2; ++ks) {
    bf16x8 bh[4], bl[4], ah[4], al[4];
    #pragma unroll
    for (int nf = 0; nf < 4; ++nf) {
      int o = (nf * 16 + l15) * 64 + ks * 32 + kq * 8;
      bh[nf] = ld8(Wh + o); bl[nf] = ld8(Wl + o);
    }
    #pragma unroll
    for (int mf = 0; mf < 4; ++mf) {
      size_t o = ((size_t)(pos0 + mf * 16 + l15)) * 64 + ks * 32 + kq * 8;
      float4 v0 = *(const float4*)&in[o];
      float4 v1 = *(const float4*)&in[o + 4];
      float xs[8] = {v0.x, v0.y, v0.z, v0.w, v1.x, v1.y, v1.z, v1.w};
      u16 th[8], tl[8];
      #pragma unroll
      for (int i = 0; i < 8; ++i) split_bf(xs[i], th[i], tl[i]);
      ah[mf] = *(const bf16x8*)th;
      al[mf] = *(const bf16x8*)tl;
    }
    #pragma unroll
    for (int mf = 0; mf < 4; ++mf)
      #pragma unroll
      for (int nf = 0; nf < 4; ++nf) {
        acc[mf][nf] = mfma16(ah[mf], bh[nf], acc[mf][nf]);
        acc[mf][nf] = mfma16(ah[mf], bl[nf], acc[mf][nf]);
        acc[mf][nf] = mfma16(al[mf], bh[nf], acc[mf][nf]);
      }
  }
  #pragma unroll
  for (int mf = 0; mf < 4; ++mf)
    #pragma unroll
    for (int nf = 0; nf < 4; ++nf) {
      int c = nf * 16 + l15;
      float bv = bias[c];
      #pragma unroll
      for (int r = 0; r < 4; ++r) {
        int pos = pos0 + mf * 16 + kq * 4 + r;
        oh[(size_t)pos * 64 + c] = f2bf_rne(acc[mf][nf][r] + bv);
      }
    }
}

// ============ out 1x1 128->64 MFMA (split weights, bf16 acts) ============
__global__ __launch_bounds__(256) void out_mfma(const u16* __restrict__ Wh,
    const u16* __restrict__ Wl, const u16* __restrict__ Gh,
    const float* __restrict__ bias, float* __restrict__ out) {
  int wv = threadIdx.x >> 6, l = threadIdx.x & 63;
  int l15 = l & 15, kq = l >> 4;
  int pos0 = blockIdx.x * 256 + wv * 64;
  f32x4 acc[4][4] = {};
  for (int ks = 0; ks < 4; ++ks) {
    bf16x8 ah[4], al[4], bh[4];
    #pragma unroll
    for (int mf = 0; mf < 4; ++mf) {
      int o = (mf * 16 + l15) * 128 + ks * 32 + kq * 8;
      ah[mf] = ld8(Wh + o); al[mf] = ld8(Wl + o);
    }
    #pragma unroll
    for (int nf = 0; nf < 4; ++nf)
      bh[nf] = ld8(Gh + ((size_t)(pos0 + nf * 16 + l15)) * 128 + ks * 32 + kq * 8);
    #pragma unroll
    for (int mf = 0; mf < 4; ++mf)
      #pragma unroll
      for (int nf = 0; nf < 4; ++nf) {
        acc[mf][nf] = mfma16(ah[mf], bh[nf], acc[mf][nf]);
        acc[mf][nf] = mfma16(al[mf], bh[nf], acc[mf][nf]);
      }
  }
  #pragma unroll
  for (int mf = 0; mf < 4; ++mf)
    #pragma unroll
    for (int r = 0; r < 4; ++r) {
      int co = mf * 16 + kq * 4 + r;
      float bv = bias[co];
      #pragma unroll
      for (int nf = 0; nf < 4; ++nf) {
        int pos = pos0 + nf * 16 + l15;
        int b = pos / 40000;
        int xy = pos - b * 40000;
        out[((size_t)(b * CC + co)) * 40000 + xy] = acc[mf][nf][r] + bv;
      }
    }
}

// ============ depth 1x1 conv 256->41 + softmax ============
__global__ __launch_bounds__(256) void dep_softmax(const float* __restrict__ in,
    const float* __restrict__ wt, const float* __restrict__ bias, float* __restrict__ depth) {
  int nh = blockIdx.x;
  int n = nh >> 4, h = nh & 15;
  __shared__ float lds[256][49];
  __shared__ float lg[ND][FW];
  int tid = threadIdx.x;
  for (int e = tid; e < 256 * 48; e += 256) {
    int ci = e % 256, w = e / 256;
    lds[ci][w] = (w < FW) ? in[((size_t)((n * FH + h) * FW + w)) * 256 + ci] : 0.f;
  }
  __syncthreads();
  int co = tid >> 2, wseg = tid & 3;
  int ob = wseg * 12;
  int nj = (wseg == 3) ? 8 : 12;
  if (co < ND) {
    float acc[12];
    #pragma unroll
    for (int j = 0; j < 12; ++j) acc[j] = 0.f;
    const float* wp = wt + co * 256;
    for (int ci = 0; ci < 256; ++ci) {
      float wv = wp[ci];
      #pragma unroll
      for (int j = 0; j < 12; ++j) acc[j] += wv * lds[ci][ob + j];
    }
    float b = bias[co];
    for (int j = 0; j < nj; ++j) lg[co][ob + j] = acc[j] + b;
  }
  __syncthreads();
  if (tid < FW) {
    int w = tid;
    float m = lg[0][w];
    #pragma unroll
    for (int d = 1; d < ND; ++d) m = fmaxf(m, lg[d][w]);
    float s = 0.f;
    #pragma unroll
    for (int d = 0; d < ND; ++d) s += expf(lg[d][w] - m);
    #pragma unroll
    for (int d = 0; d < ND; ++d)
      depth[((n * ND + d) * FH + h) * FW + w] = expf(lg[d][w] - m) / s;
  }
}

// ============ splat: one wave per (bn,d,w) ray group; run-length cell flush ============
__global__ __launch_bounds__(256) void splat(const float* __restrict__ depth,
    const float* __restrict__ img, const float* __restrict__ mats,
    const float* __restrict__ trans, const float* __restrict__ ptrans,
    float* __restrict__ bev0) {
  int gid = blockIdx.x * 4 + (threadIdx.x >> 6);
  int c = threadIdx.x & 63;
  int w = gid % FW;
  int t = gid / FW;
  int d = t % ND;
  int bn = t / ND;
  int b = bn / NCAM;
  float fx = (w == FW - 1) ? 703.0f : (float)((double)w * (703.0 / 43.0));
  float fz = (float)(4 + d);
  const float* pt = ptrans + bn * 3;
  const float* P = mats + 216 + bn * 9;
  const float* M = mats + bn * 9;
  const float* tr = trans + bn * 3;
  float px = __fsub_rn(fx, pt[0]);
  float pz = __fsub_rn(fz, pt[2]);
  const float* dp = depth + ((size_t)(bn * ND + d) * FH) * FW + w;
  const float* ip = img + ((size_t)(bn * FH) * FW + w) * CC + c;
  int cell = -1;
  float acc = 0.f;
  for (int h = 0; h < FH; ++h) {
    float fy = (float)(17 * h);
    float py = __fsub_rn(fy, pt[1]);
    float q0 = __fadd_rn(__fadd_rn(__fmul_rn(P[0], px), __fmul_rn(P[1], py)), __fmul_rn(P[2], pz));
    float q1 = __fadd_rn(__fadd_rn(__fmul_rn(P[3], px), __fmul_rn(P[4], py)), __fmul_rn(P[5], pz));
    float q2 = __fadd_rn(__fadd_rn(__fmul_rn(P[6], px), __fmul_rn(P[7], py)), __fmul_rn(P[8], pz));
    float r0 = __fmul_rn(q0, q2), r1 = __fmul_rn(q1, q2), r2 = q2;
    float u0 = __fadd_rn(__fadd_rn(__fadd_rn(__fmul_rn(M[0], r0), __fmul_rn(M[1], r1)), __fmul_rn(M[2], r2)), tr[0]);
    float u1 = __fadd_rn(__fadd_rn(__fadd_rn(__fmul_rn(M[3], r0), __fmul_rn(M[4], r1)), __fmul_rn(M[5], r2)), tr[1]);
    float u2 = __fadd_rn(__fadd_rn(__fadd_rn(__fmul_rn(M[6], r0), __fmul_rn(M[7], r1)), __fmul_rn(M[8], r2)), tr[2]);
    int gx = (int)__fmul_rn(__fadd_rn(u0, 50.0f), 2.0f);
    int gy = (int)__fmul_rn(__fadd_rn(u1, 50.0f), 2.0f);
    int gz = (int)__fdiv_rn(__fadd_rn(u2, 10.0f), 20.0f);
    bool kept = (gx >= 0 && gx < NX && gy >= 0 && gy < NX && gz == 0);
    int c2 = kept ? (b * NX + gx) * NX + gy : -1;
    if (c2 != cell) {
      if (cell >= 0) atomicAdd(&bev0[(size_t)cell * CC + c], acc);
      cell = c2;
      acc = 0.f;
    }
    if (kept)
      acc = __fadd_rn(acc, __fmul_rn(dp[h * FW], ip[(size_t)h * FW * CC]));
  }
  if (cell >= 0) atomicAdd(&bev0[(size_t)cell * CC + c], acc);
}

extern "C" void kernel_launch(void* const* d_in, const int* in_sizes, int n_in,
                              void* d_out, int out_size, void* d_ws, size_t ws_size,
                              hipStream_t stream) {
  const float* feat       = (const float*)d_in[0];
  const float* rots       = (const float*)d_in[1];
  const float* trans      = (const float*)d_in[2];
  const float* intrins    = (const float*)d_in[3];
  const float* post_trans = (const float*)d_in[5];
  const float* post_rots  = (const float*)d_in[6];
  const float* cam_w1 = (const float*)d_in[7];
  const float* cam_b1 = (const float*)d_in[8];
  const float* cam_w2 = (const float*)d_in[9];
  const float* cam_b2 = (const float*)d_in[10];
  const float* cam_wl = (const float*)d_in[11];
  const float* cam_bl = (const float*)d_in[12];
  const float* dep_w1 = (const float*)d_in[13];
  const float* dep_b1 = (const float*)d_in[14];
  const float* dep_wl = (const float*)d_in[15];
  const float* dep_bl = (const float*)d_in[16];
  const float* fus_w  = (const float*)d_in[17];
  const float* fus_b  = (const float*)d_in[18];
  const float* bev_w1 = (const float*)d_in[19];
  const float* bev_b1 = (const float*)d_in[20];
  const float* bev_w2 = (const float*)d_in[21];
  const float* bev_b2 = (const float*)d_in[22];
  const float* bev_wl = (const float*)d_in[23];
  const float* bev_bl = (const float*)d_in[24];

  char* wsb = (char*)d_ws;
  u16* featT_h = (u16*)(wsb + WS_FEATT_HI);
  u16* featT_l = (u16*)(wsb + WS_FEATT_LO);
  u16* h1_h = (u16*)(wsb + WS_H1_HI);
  u16* h2_h = (u16*)(wsb + WS_H2_HI);
  float* h1d = (float*)(wsb + WS_H1D);
  u16* bw1_h = (u16*)(wsb + WS_BW1_HI);
  u16* bw1_l = (u16*)(wsb + WS_BW1_LO);
  float* bev0 = (float*)(wsb + WS_BEV0);
  u16* cw1_h = (u16*)(wsb + WS_CW1_HI);
  u16* cw1_l = (u16*)(wsb + WS_CW1_LO);
  u16* cw2_h = (u16*)(wsb + WS_CW2_HI);
  u16* cw2_l = (u16*)(wsb + WS_CW2_LO);
  u16* cwl_h = (u16*)(wsb + WS_CWL_HI);
  u16* cwl_l = (u16*)(wsb + WS_CWL_LO);
  u16* dw1_h = (u16*)(wsb + WS_DW1_HI);
  u16* dw1_l = (u16*)(wsb + WS_DW1_LO);
  float* dep  = (float*)(wsb + WS_DEP);
  float* imgt = (float*)(wsb + WS_IMGT);
  float* mats = (float*)(wsb + WS_MATS);
  u16* fusw_h = (u16*)(wsb + WS_FUSW_HI);
  u16* fusw_l = (u16*)(wsb + WS_FUSW_LO);
  u16* bev1_h = (u16*)(wsb + WS_BEV1_HI);
  u16* hb1_h = (u16*)(wsb + WS_HB1_HI);
  u16* hb2_h = (u16*)(wsb + WS_HB2_HI);
  u16* bw2_h = (u16*)(wsb + WS_BW2_HI);
  u16* bw2_l = (u16*)(wsb + WS_BW2_LO);
  u16* bwl_h = (u16*)(wsb + WS_BWL_HI);
  u16* bwl_l = (u16*)(wsb + WS_BWL_LO);

  // prep
  featsplit<<<NBN * FH, 256, 0, stream>>>(feat, featT_h, featT_l);
  wsplit3<<<2304, 256, 0, stream>>>(cam_w1, cw1_h, cw1_l, 256, 256);
  wsplit3<<<2304, 256, 0, stream>>>(cam_w2, cw2_h, cw2_l, 256, 256);
  wsplit3<<<288, 256, 0, stream>>>(bev_w1, bw1_h, bw1_l, 128, 64);
  wsplit3<<<576, 256, 0, stream>>>(bev_w2, bw2_h, bw2_l, 128, 128);
  wsplit1<<<64, 256, 0, stream>>>(cam_wl, cwl_h, cwl_l, 64 * 256);
  wsplit1<<<256, 256, 0, stream>>>(dep_w1, dw1_h, dw1_l, 256 * 256);
  wsplit1<<<32, 256, 0, stream>>>(bev_wl, bwl_h, bwl_l, 64 * 128);
  wsplit1<<<16, 256, 0, stream>>>(fus_w, fusw_h, fusw_l, 64 * 64);
  prep_mats<<<1, 32, 0, stream>>>(rots, intrins, post_rots, mats);

  // cam encoder (MFMA, single-pass bf16, coalesced stores)
  cam_mfma<<<NBN * FH, 256, 0, stream>>>(featT_h, cw1_h, cam_b1, h1_h);
  cam_mfma<<<NBN * FH, 256, 0, stream>>>(h1_h, cw2_h, cam_b2, h2_h);
  lin_mfma<<<66, 256, 0, stream>>>(h2_h, cwl_h, cam_bl, imgt);

  // depth head (MFMA from featT planes, full 3-pass for softmax accuracy)
  dep1_mfma<<<dim3(66, 4), 256, 0, stream>>>(featT_h, featT_l, dw1_h, dw1_l, dep_b1, h1d);
  dep_softmax<<<NBN * FH, 256, 0, stream>>>(h1d, dep_wl, dep_bl, dep);

  // splat (ray-grouped)
  hipMemsetAsync((void*)bev0, 0, 40960000ul, stream);
  splat<<<(NBN * ND * FW) / 4, 256, 0, stream>>>(dep, imgt, mats, trans, post_trans, bev0);

  // fusion + BEV encoder (MFMA, single-pass bf16 convs, coalesced stores)
  fus_mfma<<<625, 256, 0, stream>>>(bev0, fusw_h, fusw_l, fus_b, bev1_h);
  bev_mfma<64><<<dim3(169, NB), 256, 0, stream>>>(bev1_h, bw1_h, bev_b1, hb1_h);
  bev_mfma<128><<<dim3(169, NB), 256, 0, stream>>>(hb1_h, bw2_h, bev_b2, hb2_h);
  out_mfma<<<625, 256, 0, stream>>>(bwl_h, bwl_l, hb2_h, bev_bl, (float*)d_out);
}

// Round 13
// 567.411 us; speedup vs baseline: 1.6940x; 1.0238x over previous
//
#include <hip/hip_runtime.h>
#include <hip/hip_bf16.h>

typedef unsigned short u16;
typedef __bf16 bf16x8 __attribute__((ext_vector_type(8)));
typedef float f32x4 __attribute__((ext_vector_type(4)));

#define NB 4
#define NCAM 6
#define NBN 24
#define CIN 256
#define CC 64
#define ND 41
#define FH 16
#define FW 44
#define NX 200
// chunk-major plane: [cc][b][y][x][32ch]; elems per plane
#define BPL ((size_t)NB * NX * NX * 32)

// ---- workspace byte offsets (overlaid; max used 164,462,592 B) ----
#define WS_FEATT_HI 0ul
#define WS_FEATT_LO 8650752ul
#define WS_H1_HI    17301504ul
#define WS_H2_HI    34603008ul
#define WS_H1D      51904512ul
#define WS_BW1_HI   69206016ul
#define WS_BW1_LO   69353472ul
#define WS_BEV0     76302336ul
#define WS_CW1_HI   117262336ul
#define WS_CW1_LO   118441984ul
#define WS_CW2_HI   119621632ul
#define WS_CW2_LO   120801280ul
#define WS_CWL_HI   121980928ul
#define WS_CWL_LO   122013696ul
#define WS_DW1_HI   122046464ul
#define WS_DW1_LO   122177536ul
#define WS_DEP      122308608ul
#define WS_IMGT     125079552ul
#define WS_MATS     129404928ul
#define WS_FUSW_HI  129406656ul
#define WS_FUSW_LO  129414848ul
#define WS_BEV1_HI  0ul            // u16 2 planes of BPL; fus->bev<64>
#define WS_HB1_HI   81920000ul     // u16 4 planes; bev<64>->bev<128>
#define WS_HB2_HI   0ul            // u16 4 planes; bev<128>->out (bev1 dead)
#define WS_BW2_HI   163840000ul
#define WS_BW2_LO   164134912ul
#define WS_BWL_HI   164429824ul
#define WS_BWL_LO   164446208ul

__device__ inline u16 f2bf_rne(float x) {
  unsigned u = __float_as_uint(x);
  unsigned r = u + 0x7fffu + ((u >> 16) & 1u);
  return (u16)(r >> 16);
}
__device__ inline float bf2f(u16 h) { return __uint_as_float(((unsigned)h) << 16); }
__device__ inline void split_bf(float x, u16& hi, u16& lo) {
  hi = f2bf_rne(x);
  lo = f2bf_rne(x - bf2f(hi));
}
__device__ inline f32x4 mfma16(bf16x8 a, bf16x8 b, f32x4 c) {
  return __builtin_amdgcn_mfma_f32_16x16x32_bf16(a, b, c, 0, 0, 0);
}
__device__ inline bf16x8 ld8(const u16* p) { return *(const bf16x8*)p; }

// ============ feat NCHW f32 -> NHWC hi/lo planes ============
__global__ __launch_bounds__(256) void featsplit(const float* __restrict__ in,
    u16* __restrict__ oh, u16* __restrict__ ol) {
  int nh = blockIdx.x;
  int n = nh >> 4, h = nh & 15;
  __shared__ float lds[256][44];
  int tid = threadIdx.x;
  for (int e = tid; e < 256 * 44; e += 256) {
    int ci = e / 44, w = e % 44;
    lds[ci][w] = in[((n * CIN + ci) * FH + h) * FW + w];
  }
  __syncthreads();
  for (int e = tid; e < 256 * 44; e += 256) {
    int w = e / 256, ci = e % 256;
    u16 hi, lo;
    split_bf(lds[ci][w], hi, lo);
    size_t o = ((size_t)((n * FH + h) * FW + w)) * 256 + ci;
    oh[o] = hi; ol[o] = lo;
  }
}

// ============ weight split 3x3 ============
__global__ __launch_bounds__(256) void wsplit3(const float* __restrict__ src,
    u16* __restrict__ dhi, u16* __restrict__ dlo, int CO, int CI_) {
  int idx = blockIdx.x * 256 + threadIdx.x;
  if (idx >= CO * CI_ * 9) return;
  int co = idx / (CI_ * 9);
  int r = idx % (CI_ * 9);
  int ci = r / 9, t = r % 9;
  u16 h, l;
  split_bf(src[idx], h, l);
  int o = (t * CO + co) * CI_ + ci;
  dhi[o] = h; dlo[o] = l;
}

// ============ weight split 1x1 ============
__global__ __launch_bounds__(256) void wsplit1(const float* __restrict__ src,
    u16* __restrict__ dhi, u16* __restrict__ dlo, int n) {
  int i = blockIdx.x * 256 + threadIdx.x;
  if (i >= n) return;
  u16 h, l;
  split_bf(src[i], h, l);
  dhi[i] = h; dlo[i] = l;
}

// ============ per-(b,n) matrices ============
__global__ void prep_mats(const float* __restrict__ rots, const float* __restrict__ intrins,
                          const float* __restrict__ post_rots, float* __restrict__ mats) {
  int bn = threadIdx.x;
  if (bn >= NBN) return;
  {
    const float* A = intrins + bn * 9;
    double a0=A[0],a1=A[1],a2=A[2],a3=A[3],a4=A[4],a5=A[5],a6=A[6],a7=A[7],a8=A[8];
    double det = a0*(a4*a8 - a5*a7) - a1*(a3*a8 - a5*a6) + a2*(a3*a7 - a4*a6);
    float inv[9];
    inv[0] = (float)((a4*a8 - a5*a7) / det);
    inv[1] = (float)((a2*a7 - a1*a8) / det);
    inv[2] = (float)((a1*a5 - a2*a4) / det);
    inv[3] = (float)((a5*a6 - a3*a8) / det);
    inv[4] = (float)((a0*a8 - a2*a6) / det);
    inv[5] = (float)((a2*a3 - a0*a5) / det);
    inv[6] = (float)((a3*a7 - a4*a6) / det);
    inv[7] = (float)((a1*a6 - a0*a7) / det);
    inv[8] = (float)((a0*a4 - a1*a3) / det);
    const float* R = rots + bn * 9;
    #pragma unroll
    for (int i = 0; i < 3; ++i)
      #pragma unroll
      for (int j = 0; j < 3; ++j) {
        float s = __fadd_rn(__fadd_rn(__fmul_rn(R[i*3+0], inv[0*3+j]),
                                      __fmul_rn(R[i*3+1], inv[1*3+j])),
                            __fmul_rn(R[i*3+2], inv[2*3+j]));
        mats[bn * 9 + i * 3 + j] = s;
      }
  }
  {
    const float* A = post_rots + bn * 9;
    double a0=A[0],a1=A[1],a2=A[2],a3=A[3],a4=A[4],a5=A[5],a6=A[6],a7=A[7],a8=A[8];
    double det = a0*(a4*a8 - a5*a7) - a1*(a3*a8 - a5*a6) + a2*(a3*a7 - a4*a6);
    float* o = mats + 216 + bn * 9;
    o[0] = (float)((a4*a8 - a5*a7) / det);
    o[1] = (float)((a2*a7 - a1*a8) / det);
    o[2] = (float)((a1*a5 - a2*a4) / det);
    o[3] = (float)((a5*a6 - a3*a8) / det);
    o[4] = (float)((a0*a8 - a2*a6) / det);
    o[5] = (float)((a2*a3 - a0*a5) / det);
    o[6] = (float)((a3*a7 - a4*a6) / det);
    o[7] = (float)((a1*a6 - a0*a7) / det);
    o[8] = (float)((a0*a4 - a1*a3) / det);
  }
}

// ============ cam 3x3 conv 256->256 + relu, MFMA single-pass bf16 ============
__global__ __launch_bounds__(256, 4) void cam_mfma(
    const u16* __restrict__ Gh,
    const u16* __restrict__ Wh,
    const float* __restrict__ bias, u16* __restrict__ Oh) {
  int nh = blockIdx.x;
  int n = nh >> 4, h = nh & 15;
  __shared__ u16 Ah[3 * 50 * 44];
  __shared__ u16 Bh[256 * 44];
  int tid = threadIdx.x;
  int wv = tid >> 6, l = tid & 63;
  int l15 = l & 15, kq = l >> 4;
  f32x4 acc[3][4] = {};
  const uint4 z4 = {0u, 0u, 0u, 0u};
  for (int cc = 0; cc < 8; ++cc) {
    __syncthreads();
    for (int e = tid; e < 600; e += 256) {
      int q = e & 3;
      int c = (e >> 2) % 50;
      int r = e / 200;
      int hh = h + r - 1, ww = c - 1;
      int off = (r * 50 + c) * 44 + q * 8;
      uint4 vh = z4;
      if (hh >= 0 && hh < FH && ww >= 0 && ww < FW) {
        size_t g = ((size_t)((n * FH + hh) * FW + ww)) * 256 + cc * 32 + q * 8;
        vh = *(const uint4*)&Gh[g];
      }
      *(uint4*)&Ah[off] = vh;
    }
    for (int t = 0; t < 9; ++t) {
      __syncthreads();
      for (int e = tid; e < 1024; e += 256) {
        int q = e & 3;
        int co = e >> 2;
        size_t g = ((size_t)(t * 256 + co)) * 256 + cc * 32 + q * 8;
        *(uint4*)&Bh[co * 44 + q * 8] = *(const uint4*)&Wh[g];
      }
      __syncthreads();
      int ty = t / 3, tx = t % 3;
      bf16x8 bh[4];
      #pragma unroll
      for (int nf = 0; nf < 4; ++nf)
        bh[nf] = *(const bf16x8*)&Bh[(wv * 64 + nf * 16 + l15) * 44 + kq * 8];
      #pragma unroll
      for (int mf = 0; mf < 3; ++mf) {
        int o = (ty * 50 + mf * 16 + l15 + tx) * 44 + kq * 8;
        bf16x8 ah = *(const bf16x8*)&Ah[o];
        #pragma unroll
        for (int nf = 0; nf < 4; ++nf)
          acc[mf][nf] = mfma16(ah, bh[nf], acc[mf][nf]);
      }
    }
  }
  __syncthreads();
  #pragma unroll
  for (int mf = 0; mf < 3; ++mf)
    #pragma unroll
    for (int nf = 0; nf < 4; ++nf) {
      int co = wv * 64 + nf * 16 + l15;
      float bv = bias[co];
      #pragma unroll
      for (int r = 0; r < 4; ++r) {
        int x = mf * 16 + kq * 4 + r;
        if (x < FW)
          Bh[x * 256 + co] = f2bf_rne(fmaxf(acc[mf][nf][r] + bv, 0.f));
      }
    }
  __syncthreads();
  for (int uid = tid; uid < FW * 32; uid += 256) {
    int x = uid >> 5, c16 = uid & 31;
    *(uint4*)&Oh[(((size_t)((n * FH + h) * FW + x)) * 256) + c16 * 8] =
        *(const uint4*)&Bh[x * 256 + c16 * 8];
  }
}

// ============ BEV 3x3 conv CI->128 + relu, MFMA single-pass bf16 ============
// Chunk-major activations: in/out are [cc][b][y][x][32] planes -> every global
// access is a dense 64B run (fixes the 2x FETCH / 3x WRITE amplification of the
// row-major [pos][C] layout whose 64B-of-256B reads thrashed L2).
template <int CI_>
__global__ __launch_bounds__(256, 3) void bev_mfma(
    const u16* __restrict__ Gh,
    const u16* __restrict__ Wh,
    const float* __restrict__ bias, u16* __restrict__ Oh) {
  int tile = blockIdx.x;
  int b = blockIdx.y;
  int y0 = (tile / 13) * 16, x0 = (tile % 13) * 16;
  __shared__ u16 Ah[18 * 18 * 32];
  __shared__ u16 Bh[128 * 44];
  int tid = threadIdx.x;
  int wv = tid >> 6, l = tid & 63;
  int l15 = l & 15, kq = l >> 4;
  f32x4 acc[4][8] = {};
  const uint4 z4 = {0u, 0u, 0u, 0u};
  for (int cc = 0; cc < CI_ / 32; ++cc) {
    __syncthreads();
    for (int e = tid; e < 1296; e += 256) {
      int q = e & 3;
      int dx = (e >> 2) % 18;
      int dy = e / 72;
      int gy = y0 + dy - 1, gx = x0 + dx - 1;
      int row = dy * 18 + dx;
      int off = row * 32 + ((q ^ ((row >> 1) & 3)) * 8);
      uint4 vh = z4;
      if (gy >= 0 && gy < NX && gx >= 0 && gx < NX) {
        size_t g = (size_t)cc * BPL + ((size_t)((b * NX + gy) * NX + gx)) * 32 + q * 8;
        vh = *(const uint4*)&Gh[g];
      }
      *(uint4*)&Ah[off] = vh;
    }
    for (int t = 0; t < 9; ++t) {
      __syncthreads();
      for (int e = tid; e < 512; e += 256) {
        int q = e & 3;
        int co = e >> 2;
        size_t g = ((size_t)(t * 128 + co)) * CI_ + cc * 32 + q * 8;
        *(uint4*)&Bh[co * 44 + q * 8] = *(const uint4*)&Wh[g];
      }
      __syncthreads();
      int ty = t / 3, tx = t % 3;
      bf16x8 bh[8];
      #pragma unroll
      for (int nf = 0; nf < 8; ++nf)
        bh[nf] = *(const bf16x8*)&Bh[(nf * 16 + l15) * 44 + kq * 8];
      #pragma unroll
      for (int mf = 0; mf < 4; ++mf) {
        int row = (wv * 4 + mf + ty) * 18 + (l15 + tx);
        int o = row * 32 + ((kq ^ ((row >> 1) & 3)) * 8);
        bf16x8 ah = *(const bf16x8*)&Ah[o];
        #pragma unroll
        for (int nf = 0; nf < 8; ++nf)
          acc[mf][nf] = mfma16(ah, bh[nf], acc[mf][nf]);
      }
    }
  }
  // --- coalesced store epilogue: per-mf slice through Ah; chunk-major planes ---
  u16* st = Ah;
  for (int mf = 0; mf < 4; ++mf) {
    __syncthreads();
    #pragma unroll
    for (int nf = 0; nf < 8; ++nf) {
      int co = nf * 16 + l15;
      float bv = bias[co];
      #pragma unroll
      for (int r = 0; r < 4; ++r) {
        int xx = kq * 4 + r;
        st[(wv * 16 + xx) * 128 + co] = f2bf_rne(fmaxf(acc[mf][nf][r] + bv, 0.f));
      }
    }
    __syncthreads();
    #pragma unroll
    for (int k = 0; k < 4; ++k) {
      int uid = tid + k * 256;
      int pos = uid >> 4, c16 = uid & 15;
      int wvp = pos >> 4, xx = pos & 15;
      int yy = y0 + wvp * 4 + mf, gx = x0 + xx;
      if (yy < NX && gx < NX) {
        int ch = c16 >> 2, qq = c16 & 3;
        *(uint4*)&Oh[(size_t)ch * BPL + ((size_t)((b * NX + yy) * NX + gx)) * 32 + qq * 8] =
            *(const uint4*)&st[pos * 128 + c16 * 8];
      }
    }
  }
}

// ============ cam 1x1 256->64 MFMA, single-pass bf16 ============
__global__ __launch_bounds__(256) void lin_mfma(const u16* __restrict__ Gh,
    const u16* __restrict__ Wh,
    const float* __restrict__ bias, float* __restrict__ out) {
  int wv = threadIdx.x >> 6, l = threadIdx.x & 63;
  int l15 = l & 15, kq = l >> 4;
  int pos0 = blockIdx.x * 256 + wv * 64;
  f32x4 acc[4][4] = {};
  for (int ks = 0; ks < 8; ++ks) {
    bf16x8 bh[4], ah[4];
    #pragma unroll
    for (int nf = 0; nf < 4; ++nf)
      bh[nf] = ld8(Wh + (nf * 16 + l15) * 256 + ks * 32 + kq * 8);
    #pragma unroll
    for (int mf = 0; mf < 4; ++mf)
      ah[mf] = ld8(Gh + ((size_t)(pos0 + mf * 16 + l15)) * 256 + ks * 32 + kq * 8);
    #pragma unroll
    for (int mf = 0; mf < 4; ++mf)
      #pragma unroll
      for (int nf = 0; nf < 4; ++nf)
        acc[mf][nf] = mfma16(ah[mf], bh[nf], acc[mf][nf]);
  }
  #pragma unroll
  for (int mf = 0; mf < 4; ++mf)
    #pragma unroll
    for (int nf = 0; nf < 4; ++nf) {
      float bv = bias[nf * 16 + l15];
      #pragma unroll
      for (int r = 0; r < 4; ++r) {
        int pos = pos0 + mf * 16 + kq * 4 + r;
        out[(size_t)pos * 64 + nf * 16 + l15] = acc[mf][nf][r] + bv;
      }
    }
}

// ============ dep 1x1 256->256 + relu MFMA (full 3-pass for softmax accuracy) ============
__global__ __launch_bounds__(256) void dep1_mfma(const u16* __restrict__ Gh,
    const u16* __restrict__ Gl, const u16* __restrict__ Wh, const u16* __restrict__ Wl,
    const float* __restrict__ bias, float* __restrict__ out) {
  int wv = threadIdx.x >> 6, l = threadIdx.x & 63;
  int l15 = l & 15, kq = l >> 4;
  int pos0 = blockIdx.x * 256 + wv * 64;
  int cog = blockIdx.y * 64;
  f32x4 acc[4][4] = {};
  for (int ks = 0; ks < 8; ++ks) {
    bf16x8 bh[4], bl[4], ah[4], al[4];
    #pragma unroll
    for (int nf = 0; nf < 4; ++nf) {
      int o = (cog + nf * 16 + l15) * 256 + ks * 32 + kq * 8;
      bh[nf] = ld8(Wh + o); bl[nf] = ld8(Wl + o);
    }
    #pragma unroll
    for (int mf = 0; mf < 4; ++mf) {
      size_t o = ((size_t)(pos0 + mf * 16 + l15)) * 256 + ks * 32 + kq * 8;
      ah[mf] = ld8(Gh + o); al[mf] = ld8(Gl + o);
    }
    #pragma unroll
    for (int mf = 0; mf < 4; ++mf)
      #pragma unroll
      for (int nf = 0; nf < 4; ++nf) {
        acc[mf][nf] = mfma16(ah[mf], bh[nf], acc[mf][nf]);
        acc[mf][nf] = mfma16(ah[mf], bl[nf], acc[mf][nf]);
        acc[mf][nf] = mfma16(al[mf], bh[nf], acc[mf][nf]);
      }
  }
  #pragma unroll
  for (int mf = 0; mf < 4; ++mf)
    #pragma unroll
    for (int nf = 0; nf < 4; ++nf) {
      int co = cog + nf * 16 + l15;
      float bv = bias[co];
      #pragma unroll
      for (int r = 0; r < 4; ++r) {
        int pos = pos0 + mf * 16 + kq * 4 + r;
        out[(size_t)pos * 256 + co] = fmaxf(acc[mf][nf][r] + bv, 0.f);
      }
    }
}

// ============ fus 1x1 64->64 MFMA (bev0 f32 split in-reg, chunk-major bf16 out) ============
__global__ __launch_bounds__(256) void fus_mfma(const float* __restrict__ in,
    const u16* __restrict__ Wh, const u16* __restrict__ Wl,
    const float* __restrict__ bias, u16* __restrict__ oh) {
  int wv = threadIdx.x >> 6, l = threadIdx.x & 63;
  int l15 = l & 15, kq = l >> 4;
  int pos0 = blockIdx.x * 256 + wv * 64;
  f32x4 acc[4][4] = {};
  for (int ks = 0; ks < 2; ++ks) {
    bf16x8 bh[4], bl[4], ah[4], al[4];
    #pragma unroll
    for (int nf = 0; nf < 4; ++nf) {
      int o = (nf * 16 + l15) * 64 + ks * 32 + kq * 8;
      bh[nf] = ld8(Wh + o); bl[nf] = ld8(Wl + o);
    }
    #pragma unroll
    for (int mf = 0; mf < 4; ++mf) {
      size_t o = ((size_t)(pos0 + mf * 16 + l15)) * 64 + ks * 32 + kq * 8;
      float4 v0 = *(const float4*)&in[o];
      float4 v1 = *(const float4*)&in[o + 4];
      float xs[8] = {v0.x, v0.y, v0.z, v0.w, v1.x, v1.y, v1.z, v1.w};
      u16 th[8], tl[8];
      #pragma unroll
      for (int i = 0; i < 8; ++i) split_bf(xs[i], th[i], tl[i]);
      ah[mf] = *(const bf16x8*)th;
      al[mf] = *(const bf16x8*)tl;
    }
    #pragma unroll
    for (int mf = 0; mf < 4; ++mf)
      #pragma unroll
      for (int nf = 0; nf < 4; ++nf) {
        acc[mf][nf] = mfma16(ah[mf], bh[nf], acc[mf][nf]);
        acc[mf][nf] = mfma16(ah[mf], bl[nf], acc[mf][nf]);
        acc[mf][nf] = mfma16(al[mf], bh[nf], acc[mf][nf]);
      }
  }
  #pragma unroll
  for (int mf = 0; mf < 4; ++mf)
    #pragma unroll
    for (int nf = 0; nf < 4; ++nf) {
      int c = nf * 16 + l15;
      int ch = c >> 5, cw = c & 31;
      float bv = bias[c];
      #pragma unroll
      for (int r = 0; r < 4; ++r) {
        int pos = pos0 + mf * 16 + kq * 4 + r;
        oh[(size_t)ch * BPL + (size_t)pos * 32 + cw] = f2bf_rne(acc[mf][nf][r] + bv);
      }
    }
}

// ============ out 1x1 128->64 MFMA (split weights, chunk-major bf16 acts) ============
__global__ __launch_bounds__(256) void out_mfma(const u16* __restrict__ Wh,
    const u16* __restrict__ Wl, const u16* __restrict__ Gh,
    const float* __restrict__ bias, float* __restrict__ out) {
  int wv = threadIdx.x >> 6, l = threadIdx.x & 63;
  int l15 = l & 15, kq = l >> 4;
  int pos0 = blockIdx.x * 256 + wv * 64;
  f32x4 acc[4][4] = {};
  for (int ks = 0; ks < 4; ++ks) {
    bf16x8 ah[4], al[4], bh[4];
    #pragma unroll
    for (int mf = 0; mf < 4; ++mf) {
      int o = (mf * 16 + l15) * 128 + ks * 32 + kq * 8;
      ah[mf] = ld8(Wh + o); al[mf] = ld8(Wl + o);
    }
    #pragma unroll
    for (int nf = 0; nf < 4; ++nf)
      bh[nf] = ld8(Gh + (size_t)ks * BPL + ((size_t)(pos0 + nf * 16 + l15)) * 32 + kq * 8);
    #pragma unroll
    for (int mf = 0; mf < 4; ++mf)
      #pragma unroll
      for (int nf = 0; nf < 4; ++nf) {
        acc[mf][nf] = mfma16(ah[mf], bh[nf], acc[mf][nf]);
        acc[mf][nf] = mfma16(al[mf], bh[nf], acc[mf][nf]);
      }
  }
  #pragma unroll
  for (int mf = 0; mf < 4; ++mf)
    #pragma unroll
    for (int r = 0; r < 4; ++r) {
      int co = mf * 16 + kq * 4 + r;
      float bv = bias[co];
      #pragma unroll
      for (int nf = 0; nf < 4; ++nf) {
        int pos = pos0 + nf * 16 + l15;
        int b = pos / 40000;
        int xy = pos - b * 40000;
        out[((size_t)(b * CC + co)) * 40000 + xy] = acc[mf][nf][r] + bv;
      }
    }
}

// ============ depth 1x1 conv 256->41 + softmax ============
__global__ __launch_bounds__(256) void dep_softmax(const float* __restrict__ in,
    const float* __restrict__ wt, const float* __restrict__ bias, float* __restrict__ depth) {
  int nh = blockIdx.x;
  int n = nh >> 4, h = nh & 15;
  __shared__ float lds[256][49];
  __shared__ float lg[ND][FW];
  int tid = threadIdx.x;
  for (int e = tid; e < 256 * 48; e += 256) {
    int ci = e % 256, w = e / 256;
    lds[ci][w] = (w < FW) ? in[((size_t)((n * FH + h) * FW + w)) * 256 + ci] : 0.f;
  }
  __syncthreads();
  int co = tid >> 2, wseg = tid & 3;
  int ob = wseg * 12;
  int nj = (wseg == 3) ? 8 : 12;
  if (co < ND) {
    float acc[12];
    #pragma unroll
    for (int j = 0; j < 12; ++j) acc[j] = 0.f;
    const float* wp = wt + co * 256;
    for (int ci = 0; ci < 256; ++ci) {
      float wv = wp[ci];
      #pragma unroll
      for (int j = 0; j < 12; ++j) acc[j] += wv * lds[ci][ob + j];
    }
    float b = bias[co];
    for (int j = 0; j < nj; ++j) lg[co][ob + j] = acc[j] + b;
  }
  __syncthreads();
  if (tid < FW) {
    int w = tid;
    float m = lg[0][w];
    #pragma unroll
    for (int d = 1; d < ND; ++d) m = fmaxf(m, lg[d][w]);
    float s = 0.f;
    #pragma unroll
    for (int d = 0; d < ND; ++d) s += expf(lg[d][w] - m);
    #pragma unroll
    for (int d = 0; d < ND; ++d)
      depth[((n * ND + d) * FH + h) * FW + w] = expf(lg[d][w] - m) / s;
  }
}

// ============ splat: one wave per (bn,d,w) ray group; run-length cell flush ============
__global__ __launch_bounds__(256) void splat(const float* __restrict__ depth,
    const float* __restrict__ img, const float* __restrict__ mats,
    const float* __restrict__ trans, const float* __restrict__ ptrans,
    float* __restrict__ bev0) {
  int gid = blockIdx.x * 4 + (threadIdx.x >> 6);
  int c = threadIdx.x & 63;
  int w = gid % FW;
  int t = gid / FW;
  int d = t % ND;
  int bn = t / ND;
  int b = bn / NCAM;
  float fx = (w == FW - 1) ? 703.0f : (float)((double)w * (703.0 / 43.0));
  float fz = (float)(4 + d);
  const float* pt = ptrans + bn * 3;
  const float* P = mats + 216 + bn * 9;
  const float* M = mats + bn * 9;
  const float* tr = trans + bn * 3;
  float px = __fsub_rn(fx, pt[0]);
  float pz = __fsub_rn(fz, pt[2]);
  const float* dp = depth + ((size_t)(bn * ND + d) * FH) * FW + w;
  const float* ip = img + ((size_t)(bn * FH) * FW + w) * CC + c;
  int cell = -1;
  float acc = 0.f;
  for (int h = 0; h < FH; ++h) {
    float fy = (float)(17 * h);
    float py = __fsub_rn(fy, pt[1]);
    float q0 = __fadd_rn(__fadd_rn(__fmul_rn(P[0], px), __fmul_rn(P[1], py)), __fmul_rn(P[2], pz));
    float q1 = __fadd_rn(__fadd_rn(__fmul_rn(P[3], px), __fmul_rn(P[4], py)), __fmul_rn(P[5], pz));
    float q2 = __fadd_rn(__fadd_rn(__fmul_rn(P[6], px), __fmul_rn(P[7], py)), __fmul_rn(P[8], pz));
    float r0 = __fmul_rn(q0, q2), r1 = __fmul_rn(q1, q2), r2 = q2;
    float u0 = __fadd_rn(__fadd_rn(__fadd_rn(__fmul_rn(M[0], r0), __fmul_rn(M[1], r1)), __fmul_rn(M[2], r2)), tr[0]);
    float u1 = __fadd_rn(__fadd_rn(__fadd_rn(__fmul_rn(M[3], r0), __fmul_rn(M[4], r1)), __fmul_rn(M[5], r2)), tr[1]);
    float u2 = __fadd_rn(__fadd_rn(__fadd_rn(__fmul_rn(M[6], r0), __fmul_rn(M[7], r1)), __fmul_rn(M[8], r2)), tr[2]);
    int gx = (int)__fmul_rn(__fadd_rn(u0, 50.0f), 2.0f);
    int gy = (int)__fmul_rn(__fadd_rn(u1, 50.0f), 2.0f);
    int gz = (int)__fdiv_rn(__fadd_rn(u2, 10.0f), 20.0f);
    bool kept = (gx >= 0 && gx < NX && gy >= 0 && gy < NX && gz == 0);
    int c2 = kept ? (b * NX + gx) * NX + gy : -1;
    if (c2 != cell) {
      if (cell >= 0) atomicAdd(&bev0[(size_t)cell * CC + c], acc);
      cell = c2;
      acc = 0.f;
    }
    if (kept)
      acc = __fadd_rn(acc, __fmul_rn(dp[h * FW], ip[(size_t)h * FW * CC]));
  }
  if (cell >= 0) atomicAdd(&bev0[(size_t)cell * CC + c], acc);
}

extern "C" void kernel_launch(void* const* d_in, const int* in_sizes, int n_in,
                              void* d_out, int out_size, void* d_ws, size_t ws_size,
                              hipStream_t stream) {
  const float* feat       = (const float*)d_in[0];
  const float* rots       = (const float*)d_in[1];
  const float* trans      = (const float*)d_in[2];
  const float* intrins    = (const float*)d_in[3];
  const float* post_trans = (const float*)d_in[5];
  const float* post_rots  = (const float*)d_in[6];
  const float* cam_w1 = (const float*)d_in[7];
  const float* cam_b1 = (const float*)d_in[8];
  const float* cam_w2 = (const float*)d_in[9];
  const float* cam_b2 = (const float*)d_in[10];
  const float* cam_wl = (const float*)d_in[11];
  const float* cam_bl = (const float*)d_in[12];
  const float* dep_w1 = (const float*)d_in[13];
  const float* dep_b1 = (const float*)d_in[14];
  const float* dep_wl = (const float*)d_in[15];
  const float* dep_bl = (const float*)d_in[16];
  const float* fus_w  = (const float*)d_in[17];
  const float* fus_b  = (const float*)d_in[18];
  const float* bev_w1 = (const float*)d_in[19];
  const float* bev_b1 = (const float*)d_in[20];
  const float* bev_w2 = (const float*)d_in[21];
  const float* bev_b2 = (const float*)d_in[22];
  const float* bev_wl = (const float*)d_in[23];
  const float* bev_bl = (const float*)d_in[24];

  char* wsb = (char*)d_ws;
  u16* featT_h = (u16*)(wsb + WS_FEATT_HI);
  u16* featT_l = (u16*)(wsb + WS_FEATT_LO);
  u16* h1_h = (u16*)(wsb + WS_H1_HI);
  u16* h2_h = (u16*)(wsb + WS_H2_HI);
  float* h1d = (float*)(wsb + WS_H1D);
  u16* bw1_h = (u16*)(wsb + WS_BW1_HI);
  u16* bw1_l = (u16*)(wsb + WS_BW1_LO);
  float* bev0 = (float*)(wsb + WS_BEV0);
  u16* cw1_h = (u16*)(wsb + WS_CW1_HI);
  u16* cw1_l = (u16*)(wsb + WS_CW1_LO);
  u16* cw2_h = (u16*)(wsb + WS_CW2_HI);
  u16* cw2_l = (u16*)(wsb + WS_CW2_LO);
  u16* cwl_h = (u16*)(wsb + WS_CWL_HI);
  u16* cwl_l = (u16*)(wsb + WS_CWL_LO);
  u16* dw1_h = (u16*)(wsb + WS_DW1_HI);
  u16* dw1_l = (u16*)(wsb + WS_DW1_LO);
  float* dep  = (float*)(wsb + WS_DEP);
  float* imgt = (float*)(wsb + WS_IMGT);
  float* mats = (float*)(wsb + WS_MATS);
  u16* fusw_h = (u16*)(wsb + WS_FUSW_HI);
  u16* fusw_l = (u16*)(wsb + WS_FUSW_LO);
  u16* bev1_h = (u16*)(wsb + WS_BEV1_HI);
  u16* hb1_h = (u16*)(wsb + WS_HB1_HI);
  u16* hb2_h = (u16*)(wsb + WS_HB2_HI);
  u16* bw2_h = (u16*)(wsb + WS_BW2_HI);
  u16* bw2_l = (u16*)(wsb + WS_BW2_LO);
  u16* bwl_h = (u16*)(wsb + WS_BWL_HI);
  u16* bwl_l = (u16*)(wsb + WS_BWL_LO);

  // prep
  featsplit<<<NBN * FH, 256, 0, stream>>>(feat, featT_h, featT_l);
  wsplit3<<<2304, 256, 0, stream>>>(cam_w1, cw1_h, cw1_l, 256, 256);
  wsplit3<<<2304, 256, 0, stream>>>(cam_w2, cw2_h, cw2_l, 256, 256);
  wsplit3<<<288, 256, 0, stream>>>(bev_w1, bw1_h, bw1_l, 128, 64);
  wsplit3<<<576, 256, 0, stream>>>(bev_w2, bw2_h, bw2_l, 128, 128);
  wsplit1<<<64, 256, 0, stream>>>(cam_wl, cwl_h, cwl_l, 64 * 256);
  wsplit1<<<256, 256, 0, stream>>>(dep_w1, dw1_h, dw1_l, 256 * 256);
  wsplit1<<<32, 256, 0, stream>>>(bev_wl, bwl_h, bwl_l, 64 * 128);
  wsplit1<<<16, 256, 0, stream>>>(fus_w, fusw_h, fusw_l, 64 * 64);
  prep_mats<<<1, 32, 0, stream>>>(rots, intrins, post_rots, mats);

  // cam encoder (MFMA, single-pass bf16)
  cam_mfma<<<NBN * FH, 256, 0, stream>>>(featT_h, cw1_h, cam_b1, h1_h);
  cam_mfma<<<NBN * FH, 256, 0, stream>>>(h1_h, cw2_h, cam_b2, h2_h);
  lin_mfma<<<66, 256, 0, stream>>>(h2_h, cwl_h, cam_bl, imgt);

  // depth head (MFMA from featT planes, full 3-pass for softmax accuracy)
  dep1_mfma<<<dim3(66, 4), 256, 0, stream>>>(featT_h, featT_l, dw1_h, dw1_l, dep_b1, h1d);
  dep_softmax<<<NBN * FH, 256, 0, stream>>>(h1d, dep_wl, dep_bl, dep);

  // splat (ray-grouped)
  hipMemsetAsync((void*)bev0, 0, 40960000ul, stream);
  splat<<<(NBN * ND * FW) / 4, 256, 0, stream>>>(dep, imgt, mats, trans, post_trans, bev0);

  // fusion + BEV encoder (MFMA, single-pass bf16 convs, chunk-major activations)
  fus_mfma<<<625, 256, 0, stream>>>(bev0, fusw_h, fusw_l, fus_b, bev1_h);
  bev_mfma<64><<<dim3(169, NB), 256, 0, stream>>>(bev1_h, bw1_h, bev_b1, hb1_h);
  bev_mfma<128><<<dim3(169, NB), 256, 0, stream>>>(hb1_h, bw2_h, bev_b2, hb2_h);
  out_mfma<<<625, 256, 0, stream>>>(bwl_h, bwl_l, hb2_h, bev_bl, (float*)d_out);
}

// Round 14
// 531.671 us; speedup vs baseline: 1.8079x; 1.0672x over previous
//
#include <hip/hip_runtime.h>
#include <hip/hip_bf16.h>

typedef unsigned short u16;
typedef __bf16 bf16x8 __attribute__((ext_vector_type(8)));
typedef float f32x4 __attribute__((ext_vector_type(4)));

#define NB 4
#define NCAM 6
#define NBN 24
#define CIN 256
#define CC 64
#define ND 41
#define FH 16
#define FW 44
#define NX 200
// chunk-major plane: [cc][b][y][x][32ch]; elems per plane
#define BPL ((size_t)NB * NX * NX * 32)

// ---- workspace byte offsets (overlaid; max used 164,462,592 B) ----
#define WS_FEATT_HI 0ul
#define WS_FEATT_LO 8650752ul
#define WS_H1_HI    17301504ul
#define WS_H2_HI    34603008ul
#define WS_H1D      51904512ul
#define WS_BW1_HI   69206016ul
#define WS_BW1_LO   69353472ul
#define WS_BEV0     76302336ul
#define WS_CW1_HI   117262336ul
#define WS_CW1_LO   118441984ul
#define WS_CW2_HI   119621632ul
#define WS_CW2_LO   120801280ul
#define WS_CWL_HI   121980928ul
#define WS_CWL_LO   122013696ul
#define WS_DW1_HI   122046464ul
#define WS_DW1_LO   122177536ul
#define WS_DEP      122308608ul
#define WS_IMGT     125079552ul
#define WS_MATS     129404928ul
#define WS_FUSW_HI  129406656ul
#define WS_FUSW_LO  129414848ul
#define WS_BEV1_HI  0ul            // u16 2 planes of BPL; fus->bev<64>
#define WS_HB1_HI   81920000ul     // u16 4 planes; bev<64>->bev<128>
#define WS_HB2_HI   0ul            // u16 4 planes; bev<128>->out (bev1 dead)
#define WS_BW2_HI   163840000ul
#define WS_BW2_LO   164134912ul
#define WS_BWL_HI   164429824ul
#define WS_BWL_LO   164446208ul

__device__ inline u16 f2bf_rne(float x) {
  unsigned u = __float_as_uint(x);
  unsigned r = u + 0x7fffu + ((u >> 16) & 1u);
  return (u16)(r >> 16);
}
__device__ inline float bf2f(u16 h) { return __uint_as_float(((unsigned)h) << 16); }
__device__ inline void split_bf(float x, u16& hi, u16& lo) {
  hi = f2bf_rne(x);
  lo = f2bf_rne(x - bf2f(hi));
}
__device__ inline f32x4 mfma16(bf16x8 a, bf16x8 b, f32x4 c) {
  return __builtin_amdgcn_mfma_f32_16x16x32_bf16(a, b, c, 0, 0, 0);
}
__device__ inline bf16x8 ld8(const u16* p) { return *(const bf16x8*)p; }

// ============ feat NCHW f32 -> NHWC hi/lo planes ============
__global__ __launch_bounds__(256) void featsplit(const float* __restrict__ in,
    u16* __restrict__ oh, u16* __restrict__ ol) {
  int nh = blockIdx.x;
  int n = nh >> 4, h = nh & 15;
  __shared__ float lds[256][44];
  int tid = threadIdx.x;
  for (int e = tid; e < 256 * 44; e += 256) {
    int ci = e / 44, w = e % 44;
    lds[ci][w] = in[((n * CIN + ci) * FH + h) * FW + w];
  }
  __syncthreads();
  for (int e = tid; e < 256 * 44; e += 256) {
    int w = e / 256, ci = e % 256;
    u16 hi, lo;
    split_bf(lds[ci][w], hi, lo);
    size_t o = ((size_t)((n * FH + h) * FW + w)) * 256 + ci;
    oh[o] = hi; ol[o] = lo;
  }
}

// ============ weight split 3x3 ============
__global__ __launch_bounds__(256) void wsplit3(const float* __restrict__ src,
    u16* __restrict__ dhi, u16* __restrict__ dlo, int CO, int CI_) {
  int idx = blockIdx.x * 256 + threadIdx.x;
  if (idx >= CO * CI_ * 9) return;
  int co = idx / (CI_ * 9);
  int r = idx % (CI_ * 9);
  int ci = r / 9, t = r % 9;
  u16 h, l;
  split_bf(src[idx], h, l);
  int o = (t * CO + co) * CI_ + ci;
  dhi[o] = h; dlo[o] = l;
}

// ============ weight split 1x1 ============
__global__ __launch_bounds__(256) void wsplit1(const float* __restrict__ src,
    u16* __restrict__ dhi, u16* __restrict__ dlo, int n) {
  int i = blockIdx.x * 256 + threadIdx.x;
  if (i >= n) return;
  u16 h, l;
  split_bf(src[i], h, l);
  dhi[i] = h; dlo[i] = l;
}

// ============ per-(b,n) matrices ============
__global__ void prep_mats(const float* __restrict__ rots, const float* __restrict__ intrins,
                          const float* __restrict__ post_rots, float* __restrict__ mats) {
  int bn = threadIdx.x;
  if (bn >= NBN) return;
  {
    const float* A = intrins + bn * 9;
    double a0=A[0],a1=A[1],a2=A[2],a3=A[3],a4=A[4],a5=A[5],a6=A[6],a7=A[7],a8=A[8];
    double det = a0*(a4*a8 - a5*a7) - a1*(a3*a8 - a5*a6) + a2*(a3*a7 - a4*a6);
    float inv[9];
    inv[0] = (float)((a4*a8 - a5*a7) / det);
    inv[1] = (float)((a2*a7 - a1*a8) / det);
    inv[2] = (float)((a1*a5 - a2*a4) / det);
    inv[3] = (float)((a5*a6 - a3*a8) / det);
    inv[4] = (float)((a0*a8 - a2*a6) / det);
    inv[5] = (float)((a2*a3 - a0*a5) / det);
    inv[6] = (float)((a3*a7 - a4*a6) / det);
    inv[7] = (float)((a1*a6 - a0*a7) / det);
    inv[8] = (float)((a0*a4 - a1*a3) / det);
    const float* R = rots + bn * 9;
    #pragma unroll
    for (int i = 0; i < 3; ++i)
      #pragma unroll
      for (int j = 0; j < 3; ++j) {
        float s = __fadd_rn(__fadd_rn(__fmul_rn(R[i*3+0], inv[0*3+j]),
                                      __fmul_rn(R[i*3+1], inv[1*3+j])),
                            __fmul_rn(R[i*3+2], inv[2*3+j]));
        mats[bn * 9 + i * 3 + j] = s;
      }
  }
  {
    const float* A = post_rots + bn * 9;
    double a0=A[0],a1=A[1],a2=A[2],a3=A[3],a4=A[4],a5=A[5],a6=A[6],a7=A[7],a8=A[8];
    double det = a0*(a4*a8 - a5*a7) - a1*(a3*a8 - a5*a6) + a2*(a3*a7 - a4*a6);
    float* o = mats + 216 + bn * 9;
    o[0] = (float)((a4*a8 - a5*a7) / det);
    o[1] = (float)((a2*a7 - a1*a8) / det);
    o[2] = (float)((a1*a5 - a2*a4) / det);
    o[3] = (float)((a5*a6 - a3*a8) / det);
    o[4] = (float)((a0*a8 - a2*a6) / det);
    o[5] = (float)((a2*a3 - a0*a5) / det);
    o[6] = (float)((a3*a7 - a4*a6) / det);
    o[7] = (float)((a1*a6 - a0*a7) / det);
    o[8] = (float)((a0*a4 - a1*a3) / det);
  }
}

// ============ cam 3x3 conv 256->256 + relu, MFMA single-pass bf16, tap-paired ============
// Two taps of B staged per barrier pair: 88 barriers/block (was 152). LDS 58.3 KB;
// grid 384 fills only ~1.5 blocks/CU so 2/CU occupancy cap is not binding.
__global__ __launch_bounds__(256, 2) void cam_mfma(
    const u16* __restrict__ Gh,
    const u16* __restrict__ Wh,
    const float* __restrict__ bias, u16* __restrict__ Oh) {
  int nh = blockIdx.x;
  int n = nh >> 4, h = nh & 15;
  __shared__ u16 Ah[3 * 50 * 44];
  __shared__ u16 Bh[2][256 * 44];
  int tid = threadIdx.x;
  int wv = tid >> 6, l = tid & 63;
  int l15 = l & 15, kq = l >> 4;
  f32x4 acc[3][4] = {};
  const uint4 z4 = {0u, 0u, 0u, 0u};
  for (int cc = 0; cc < 8; ++cc) {
    __syncthreads();   // prev compute done reading Ah
    for (int e = tid; e < 600; e += 256) {
      int q = e & 3;
      int c = (e >> 2) % 50;
      int r = e / 200;
      int hh = h + r - 1, ww = c - 1;
      int off = (r * 50 + c) * 44 + q * 8;
      uint4 vh = z4;
      if (hh >= 0 && hh < FH && ww >= 0 && ww < FW) {
        size_t g = ((size_t)((n * FH + hh) * FW + ww)) * 256 + cc * 32 + q * 8;
        vh = *(const uint4*)&Gh[g];
      }
      *(uint4*)&Ah[off] = vh;
    }
    for (int p = 0; p < 5; ++p) {
      int t0 = 2 * p;
      int nt = (t0 + 1 < 9) ? 2 : 1;
      __syncthreads();   // prev compute done reading Bh (also orders A-stage for p==0)
      for (int e = tid; e < nt * 1024; e += 256) {
        int tp = e >> 10;
        int rem = e & 1023;
        int q = rem & 3, co = rem >> 2;
        size_t g = ((size_t)((t0 + tp) * 256 + co)) * 256 + cc * 32 + q * 8;
        *(uint4*)&Bh[tp][co * 44 + q * 8] = *(const uint4*)&Wh[g];
      }
      __syncthreads();
      for (int tp = 0; tp < nt; ++tp) {
        int t = t0 + tp;
        int ty = t / 3, tx = t % 3;
        bf16x8 bh[4];
        #pragma unroll
        for (int nf = 0; nf < 4; ++nf)
          bh[nf] = *(const bf16x8*)&Bh[tp][(wv * 64 + nf * 16 + l15) * 44 + kq * 8];
        #pragma unroll
        for (int mf = 0; mf < 3; ++mf) {
          int o = (ty * 50 + mf * 16 + l15 + tx) * 44 + kq * 8;
          bf16x8 ah = *(const bf16x8*)&Ah[o];
          #pragma unroll
          for (int nf = 0; nf < 4; ++nf)
            acc[mf][nf] = mfma16(ah, bh[nf], acc[mf][nf]);
        }
      }
    }
  }
  __syncthreads();
  #pragma unroll
  for (int mf = 0; mf < 3; ++mf)
    #pragma unroll
    for (int nf = 0; nf < 4; ++nf) {
      int co = wv * 64 + nf * 16 + l15;
      float bv = bias[co];
      #pragma unroll
      for (int r = 0; r < 4; ++r) {
        int x = mf * 16 + kq * 4 + r;
        if (x < FW)
          Bh[0][x * 256 + co] = f2bf_rne(fmaxf(acc[mf][nf][r] + bv, 0.f));
      }
    }
  __syncthreads();
  for (int uid = tid; uid < FW * 32; uid += 256) {
    int x = uid >> 5, c16 = uid & 31;
    *(uint4*)&Oh[(((size_t)((n * FH + h) * FW + x)) * 256) + c16 * 8] =
        *(const uint4*)&Bh[0][x * 256 + c16 * 8];
  }
}

// ============ BEV 3x3 conv CI->128 + relu, MFMA single-pass bf16, tap-paired ============
// Chunk-major activations; two B-taps per barrier pair: 44 barriers (<128>, was 76).
// LDS 43.3 KB -> keeps 3 blocks/CU. acc[4][8]=128 regs: 3 waves/EU, never more.
template <int CI_>
__global__ __launch_bounds__(256, 3) void bev_mfma(
    const u16* __restrict__ Gh,
    const u16* __restrict__ Wh,
    const float* __restrict__ bias, u16* __restrict__ Oh) {
  int tile = blockIdx.x;
  int b = blockIdx.y;
  int y0 = (tile / 13) * 16, x0 = (tile % 13) * 16;
  __shared__ u16 Ah[18 * 18 * 32];
  __shared__ u16 Bh[2][128 * 44];
  int tid = threadIdx.x;
  int wv = tid >> 6, l = tid & 63;
  int l15 = l & 15, kq = l >> 4;
  f32x4 acc[4][8] = {};
  const uint4 z4 = {0u, 0u, 0u, 0u};
  for (int cc = 0; cc < CI_ / 32; ++cc) {
    __syncthreads();   // prev compute done reading Ah
    for (int e = tid; e < 1296; e += 256) {
      int q = e & 3;
      int dx = (e >> 2) % 18;
      int dy = e / 72;
      int gy = y0 + dy - 1, gx = x0 + dx - 1;
      int row = dy * 18 + dx;
      int off = row * 32 + ((q ^ ((row >> 1) & 3)) * 8);
      uint4 vh = z4;
      if (gy >= 0 && gy < NX && gx >= 0 && gx < NX) {
        size_t g = (size_t)cc * BPL + ((size_t)((b * NX + gy) * NX + gx)) * 32 + q * 8;
        vh = *(const uint4*)&Gh[g];
      }
      *(uint4*)&Ah[off] = vh;
    }
    for (int p = 0; p < 5; ++p) {
      int t0 = 2 * p;
      int nt = (t0 + 1 < 9) ? 2 : 1;
      __syncthreads();
      for (int e = tid; e < nt * 512; e += 256) {
        int tp = e >> 9;
        int rem = e & 511;
        int q = rem & 3, co = rem >> 2;
        size_t g = ((size_t)((t0 + tp) * 128 + co)) * CI_ + cc * 32 + q * 8;
        *(uint4*)&Bh[tp][co * 44 + q * 8] = *(const uint4*)&Wh[g];
      }
      __syncthreads();
      for (int tp = 0; tp < nt; ++tp) {
        int t = t0 + tp;
        int ty = t / 3, tx = t % 3;
        bf16x8 bh[8];
        #pragma unroll
        for (int nf = 0; nf < 8; ++nf)
          bh[nf] = *(const bf16x8*)&Bh[tp][(nf * 16 + l15) * 44 + kq * 8];
        #pragma unroll
        for (int mf = 0; mf < 4; ++mf) {
          int row = (wv * 4 + mf + ty) * 18 + (l15 + tx);
          int o = row * 32 + ((kq ^ ((row >> 1) & 3)) * 8);
          bf16x8 ah = *(const bf16x8*)&Ah[o];
          #pragma unroll
          for (int nf = 0; nf < 8; ++nf)
            acc[mf][nf] = mfma16(ah, bh[nf], acc[mf][nf]);
        }
      }
    }
  }
  // --- coalesced store epilogue: per-mf slice through Ah; chunk-major planes ---
  u16* st = Ah;
  for (int mf = 0; mf < 4; ++mf) {
    __syncthreads();
    #pragma unroll
    for (int nf = 0; nf < 8; ++nf) {
      int co = nf * 16 + l15;
      float bv = bias[co];
      #pragma unroll
      for (int r = 0; r < 4; ++r) {
        int xx = kq * 4 + r;
        st[(wv * 16 + xx) * 128 + co] = f2bf_rne(fmaxf(acc[mf][nf][r] + bv, 0.f));
      }
    }
    __syncthreads();
    #pragma unroll
    for (int k = 0; k < 4; ++k) {
      int uid = tid + k * 256;
      int pos = uid >> 4, c16 = uid & 15;
      int wvp = pos >> 4, xx = pos & 15;
      int yy = y0 + wvp * 4 + mf, gx = x0 + xx;
      if (yy < NX && gx < NX) {
        int ch = c16 >> 2, qq = c16 & 3;
        *(uint4*)&Oh[(size_t)ch * BPL + ((size_t)((b * NX + yy) * NX + gx)) * 32 + qq * 8] =
            *(const uint4*)&st[pos * 128 + c16 * 8];
      }
    }
  }
}

// ============ cam 1x1 256->64 MFMA, single-pass bf16 ============
__global__ __launch_bounds__(256) void lin_mfma(const u16* __restrict__ Gh,
    const u16* __restrict__ Wh,
    const float* __restrict__ bias, float* __restrict__ out) {
  int wv = threadIdx.x >> 6, l = threadIdx.x & 63;
  int l15 = l & 15, kq = l >> 4;
  int pos0 = blockIdx.x * 256 + wv * 64;
  f32x4 acc[4][4] = {};
  for (int ks = 0; ks < 8; ++ks) {
    bf16x8 bh[4], ah[4];
    #pragma unroll
    for (int nf = 0; nf < 4; ++nf)
      bh[nf] = ld8(Wh + (nf * 16 + l15) * 256 + ks * 32 + kq * 8);
    #pragma unroll
    for (int mf = 0; mf < 4; ++mf)
      ah[mf] = ld8(Gh + ((size_t)(pos0 + mf * 16 + l15)) * 256 + ks * 32 + kq * 8);
    #pragma unroll
    for (int mf = 0; mf < 4; ++mf)
      #pragma unroll
      for (int nf = 0; nf < 4; ++nf)
        acc[mf][nf] = mfma16(ah[mf], bh[nf], acc[mf][nf]);
  }
  #pragma unroll
  for (int mf = 0; mf < 4; ++mf)
    #pragma unroll
    for (int nf = 0; nf < 4; ++nf) {
      float bv = bias[nf * 16 + l15];
      #pragma unroll
      for (int r = 0; r < 4; ++r) {
        int pos = pos0 + mf * 16 + kq * 4 + r;
        out[(size_t)pos * 64 + nf * 16 + l15] = acc[mf][nf][r] + bv;
      }
    }
}

// ============ dep 1x1 256->256 + relu MFMA (full 3-pass for softmax accuracy) ============
__global__ __launch_bounds__(256) void dep1_mfma(const u16* __restrict__ Gh,
    const u16* __restrict__ Gl, const u16* __restrict__ Wh, const u16* __restrict__ Wl,
    const float* __restrict__ bias, float* __restrict__ out) {
  int wv = threadIdx.x >> 6, l = threadIdx.x & 63;
  int l15 = l & 15, kq = l >> 4;
  int pos0 = blockIdx.x * 256 + wv * 64;
  int cog = blockIdx.y * 64;
  f32x4 acc[4][4] = {};
  for (int ks = 0; ks < 8; ++ks) {
    bf16x8 bh[4], bl[4], ah[4], al[4];
    #pragma unroll
    for (int nf = 0; nf < 4; ++nf) {
      int o = (cog + nf * 16 + l15) * 256 + ks * 32 + kq * 8;
      bh[nf] = ld8(Wh + o); bl[nf] = ld8(Wl + o);
    }
    #pragma unroll
    for (int mf = 0; mf < 4; ++mf) {
      size_t o = ((size_t)(pos0 + mf * 16 + l15)) * 256 + ks * 32 + kq * 8;
      ah[mf] = ld8(Gh + o); al[mf] = ld8(Gl + o);
    }
    #pragma unroll
    for (int mf = 0; mf < 4; ++mf)
      #pragma unroll
      for (int nf = 0; nf < 4; ++nf) {
        acc[mf][nf] = mfma16(ah[mf], bh[nf], acc[mf][nf]);
        acc[mf][nf] = mfma16(ah[mf], bl[nf], acc[mf][nf]);
        acc[mf][nf] = mfma16(al[mf], bh[nf], acc[mf][nf]);
      }
  }
  #pragma unroll
  for (int mf = 0; mf < 4; ++mf)
    #pragma unroll
    for (int nf = 0; nf < 4; ++nf) {
      int co = cog + nf * 16 + l15;
      float bv = bias[co];
      #pragma unroll
      for (int r = 0; r < 4; ++r) {
        int pos = pos0 + mf * 16 + kq * 4 + r;
        out[(size_t)pos * 256 + co] = fmaxf(acc[mf][nf][r] + bv, 0.f);
      }
    }
}

// ============ fus 1x1 64->64 MFMA (bev0 f32 split in-reg, chunk-major bf16 out) ============
__global__ __launch_bounds__(256) void fus_mfma(const float* __restrict__ in,
    const u16* __restrict__ Wh, const u16* __restrict__ Wl,
    const float* __restrict__ bias, u16* __restrict__ oh) {
  int wv = threadIdx.x >> 6, l = threadIdx.x & 63;
  int l15 = l & 15, kq = l >> 4;
  int pos0 = blockIdx.x * 256 + wv * 64;
  f32x4 acc[4][4] = {};
  for (int ks = 0; ks < 2; ++ks) {
    bf16x8 bh[4], bl[4], ah[4], al[4];
    #pragma unroll
    for (int nf = 0; nf < 4; ++nf) {
      int o = (nf * 16 + l15) * 64 + ks * 32 + kq * 8;
      bh[nf] = ld8(Wh + o); bl[nf] = ld8(Wl + o);
    }
    #pragma unroll
    for (int mf = 0; mf < 4; ++mf) {
      size_t o = ((size_t)(pos0 + mf * 16 + l15)) * 64 + ks * 32 + kq * 8;
      float4 v0 = *(const float4*)&in[o];
      float4 v1 = *(const float4*)&in[o + 4];
      float xs[8] = {v0.x, v0.y, v0.z, v0.w, v1.x, v1.y, v1.z, v1.w};
      u16 th[8], tl[8];
      #pragma unroll
      for (int i = 0; i < 8; ++i) split_bf(xs[i], th[i], tl[i]);
      ah[mf] = *(const bf16x8*)th;
      al[mf] = *(const bf16x8*)tl;
    }
    #pragma unroll
    for (int mf = 0; mf < 4; ++mf)
      #pragma unroll
      for (int nf = 0; nf < 4; ++nf) {
        acc[mf][nf] = mfma16(ah[mf], bh[nf], acc[mf][nf]);
        acc[mf][nf] = mfma16(ah[mf], bl[nf], acc[mf][nf]);
        acc[mf][nf] = mfma16(al[mf], bh[nf], acc[mf][nf]);
      }
  }
  #pragma unroll
  for (int mf = 0; mf < 4; ++mf)
    #pragma unroll
    for (int nf = 0; nf < 4; ++nf) {
      int c = nf * 16 + l15;
      int ch = c >> 5, cw = c & 31;
      float bv = bias[c];
      #pragma unroll
      for (int r = 0; r < 4; ++r) {
        int pos = pos0 + mf * 16 + kq * 4 + r;
        oh[(size_t)ch * BPL + (size_t)pos * 32 + cw] = f2bf_rne(acc[mf][nf][r] + bv);
      }
    }
}

// ============ out 1x1 128->64 MFMA (split weights, chunk-major bf16 acts) ============
__global__ __launch_bounds__(256) void out_mfma(const u16* __restrict__ Wh,
    const u16* __restrict__ Wl, const u16* __restrict__ Gh,
    const float* __restrict__ bias, float* __restrict__ out) {
  int wv = threadIdx.x >> 6, l = threadIdx.x & 63;
  int l15 = l & 15, kq = l >> 4;
  int pos0 = blockIdx.x * 256 + wv * 64;
  f32x4 acc[4][4] = {};
  for (int ks = 0; ks < 4; ++ks) {
    bf16x8 ah[4], al[4], bh[4];
    #pragma unroll
    for (int mf = 0; mf < 4; ++mf) {
      int o = (mf * 16 + l15) * 128 + ks * 32 + kq * 8;
      ah[mf] = ld8(Wh + o); al[mf] = ld8(Wl + o);
    }
    #pragma unroll
    for (int nf = 0; nf < 4; ++nf)
      bh[nf] = ld8(Gh + (size_t)ks * BPL + ((size_t)(pos0 + nf * 16 + l15)) * 32 + kq * 8);
    #pragma unroll
    for (int mf = 0; mf < 4; ++mf)
      #pragma unroll
      for (int nf = 0; nf < 4; ++nf) {
        acc[mf][nf] = mfma16(ah[mf], bh[nf], acc[mf][nf]);
        acc[mf][nf] = mfma16(al[mf], bh[nf], acc[mf][nf]);
      }
  }
  #pragma unroll
  for (int mf = 0; mf < 4; ++mf)
    #pragma unroll
    for (int r = 0; r < 4; ++r) {
      int co = mf * 16 + kq * 4 + r;
      float bv = bias[co];
      #pragma unroll
      for (int nf = 0; nf < 4; ++nf) {
        int pos = pos0 + nf * 16 + l15;
        int b = pos / 40000;
        int xy = pos - b * 40000;
        out[((size_t)(b * CC + co)) * 40000 + xy] = acc[mf][nf][r] + bv;
      }
    }
}

// ============ depth 1x1 conv 256->41 + softmax ============
__global__ __launch_bounds__(256) void dep_softmax(const float* __restrict__ in,
    const float* __restrict__ wt, const float* __restrict__ bias, float* __restrict__ depth) {
  int nh = blockIdx.x;
  int n = nh >> 4, h = nh & 15;
  __shared__ float lds[256][49];
  __shared__ float lg[ND][FW];
  int tid = threadIdx.x;
  for (int e = tid; e < 256 * 48; e += 256) {
    int ci = e % 256, w = e / 256;
    lds[ci][w] = (w < FW) ? in[((size_t)((n * FH + h) * FW + w)) * 256 + ci] : 0.f;
  }
  __syncthreads();
  int co = tid >> 2, wseg = tid & 3;
  int ob = wseg * 12;
  int nj = (wseg == 3) ? 8 : 12;
  if (co < ND) {
    float acc[12];
    #pragma unroll
    for (int j = 0; j < 12; ++j) acc[j] = 0.f;
    const float* wp = wt + co * 256;
    for (int ci = 0; ci < 256; ++ci) {
      float wv = wp[ci];
      #pragma unroll
      for (int j = 0; j < 12; ++j) acc[j] += wv * lds[ci][ob + j];
    }
    float b = bias[co];
    for (int j = 0; j < nj; ++j) lg[co][ob + j] = acc[j] + b;
  }
  __syncthreads();
  if (tid < FW) {
    int w = tid;
    float m = lg[0][w];
    #pragma unroll
    for (int d = 1; d < ND; ++d) m = fmaxf(m, lg[d][w]);
    float s = 0.f;
    #pragma unroll
    for (int d = 0; d < ND; ++d) s += expf(lg[d][w] - m);
    #pragma unroll
    for (int d = 0; d < ND; ++d)
      depth[((n * ND + d) * FH + h) * FW + w] = expf(lg[d][w] - m) / s;
  }
}

// ============ splat: one wave per (bn,d,w) ray group; run-length cell flush ============
__global__ __launch_bounds__(256) void splat(const float* __restrict__ depth,
    const float* __restrict__ img, const float* __restrict__ mats,
    const float* __restrict__ trans, const float* __restrict__ ptrans,
    float* __restrict__ bev0) {
  int gid = blockIdx.x * 4 + (threadIdx.x >> 6);
  int c = threadIdx.x & 63;
  int w = gid % FW;
  int t = gid / FW;
  int d = t % ND;
  int bn = t / ND;
  int b = bn / NCAM;
  float fx = (w == FW - 1) ? 703.0f : (float)((double)w * (703.0 / 43.0));
  float fz = (float)(4 + d);
  const float* pt = ptrans + bn * 3;
  const float* P = mats + 216 + bn * 9;
  const float* M = mats + bn * 9;
  const float* tr = trans + bn * 3;
  float px = __fsub_rn(fx, pt[0]);
  float pz = __fsub_rn(fz, pt[2]);
  const float* dp = depth + ((size_t)(bn * ND + d) * FH) * FW + w;
  const float* ip = img + ((size_t)(bn * FH) * FW + w) * CC + c;
  int cell = -1;
  float acc = 0.f;
  for (int h = 0; h < FH; ++h) {
    float fy = (float)(17 * h);
    float py = __fsub_rn(fy, pt[1]);
    float q0 = __fadd_rn(__fadd_rn(__fmul_rn(P[0], px), __fmul_rn(P[1], py)), __fmul_rn(P[2], pz));
    float q1 = __fadd_rn(__fadd_rn(__fmul_rn(P[3], px), __fmul_rn(P[4], py)), __fmul_rn(P[5], pz));
    float q2 = __fadd_rn(__fadd_rn(__fmul_rn(P[6], px), __fmul_rn(P[7], py)), __fmul_rn(P[8], pz));
    float r0 = __fmul_rn(q0, q2), r1 = __fmul_rn(q1, q2), r2 = q2;
    float u0 = __fadd_rn(__fadd_rn(__fadd_rn(__fmul_rn(M[0], r0), __fmul_rn(M[1], r1)), __fmul_rn(M[2], r2)), tr[0]);
    float u1 = __fadd_rn(__fadd_rn(__fadd_rn(__fmul_rn(M[3], r0), __fmul_rn(M[4], r1)), __fmul_rn(M[5], r2)), tr[1]);
    float u2 = __fadd_rn(__fadd_rn(__fadd_rn(__fmul_rn(M[6], r0), __fmul_rn(M[7], r1)), __fmul_rn(M[8], r2)), tr[2]);
    int gx = (int)__fmul_rn(__fadd_rn(u0, 50.0f), 2.0f);
    int gy = (int)__fmul_rn(__fadd_rn(u1, 50.0f), 2.0f);
    int gz = (int)__fdiv_rn(__fadd_rn(u2, 10.0f), 20.0f);
    bool kept = (gx >= 0 && gx < NX && gy >= 0 && gy < NX && gz == 0);
    int c2 = kept ? (b * NX + gx) * NX + gy : -1;
    if (c2 != cell) {
      if (cell >= 0) atomicAdd(&bev0[(size_t)cell * CC + c], acc);
      cell = c2;
      acc = 0.f;
    }
    if (kept)
      acc = __fadd_rn(acc, __fmul_rn(dp[h * FW], ip[(size_t)h * FW * CC]));
  }
  if (cell >= 0) atomicAdd(&bev0[(size_t)cell * CC + c], acc);
}

extern "C" void kernel_launch(void* const* d_in, const int* in_sizes, int n_in,
                              void* d_out, int out_size, void* d_ws, size_t ws_size,
                              hipStream_t stream) {
  const float* feat       = (const float*)d_in[0];
  const float* rots       = (const float*)d_in[1];
  const float* trans      = (const float*)d_in[2];
  const float* intrins    = (const float*)d_in[3];
  const float* post_trans = (const float*)d_in[5];
  const float* post_rots  = (const float*)d_in[6];
  const float* cam_w1 = (const float*)d_in[7];
  const float* cam_b1 = (const float*)d_in[8];
  const float* cam_w2 = (const float*)d_in[9];
  const float* cam_b2 = (const float*)d_in[10];
  const float* cam_wl = (const float*)d_in[11];
  const float* cam_bl = (const float*)d_in[12];
  const float* dep_w1 = (const float*)d_in[13];
  const float* dep_b1 = (const float*)d_in[14];
  const float* dep_wl = (const float*)d_in[15];
  const float* dep_bl = (const float*)d_in[16];
  const float* fus_w  = (const float*)d_in[17];
  const float* fus_b  = (const float*)d_in[18];
  const float* bev_w1 = (const float*)d_in[19];
  const float* bev_b1 = (const float*)d_in[20];
  const float* bev_w2 = (const float*)d_in[21];
  const float* bev_b2 = (const float*)d_in[22];
  const float* bev_wl = (const float*)d_in[23];
  const float* bev_bl = (const float*)d_in[24];

  char* wsb = (char*)d_ws;
  u16* featT_h = (u16*)(wsb + WS_FEATT_HI);
  u16* featT_l = (u16*)(wsb + WS_FEATT_LO);
  u16* h1_h = (u16*)(wsb + WS_H1_HI);
  u16* h2_h = (u16*)(wsb + WS_H2_HI);
  float* h1d = (float*)(wsb + WS_H1D);
  u16* bw1_h = (u16*)(wsb + WS_BW1_HI);
  u16* bw1_l = (u16*)(wsb + WS_BW1_LO);
  float* bev0 = (float*)(wsb + WS_BEV0);
  u16* cw1_h = (u16*)(wsb + WS_CW1_HI);
  u16* cw1_l = (u16*)(wsb + WS_CW1_LO);
  u16* cw2_h = (u16*)(wsb + WS_CW2_HI);
  u16* cw2_l = (u16*)(wsb + WS_CW2_LO);
  u16* cwl_h = (u16*)(wsb + WS_CWL_HI);
  u16* cwl_l = (u16*)(wsb + WS_CWL_LO);
  u16* dw1_h = (u16*)(wsb + WS_DW1_HI);
  u16* dw1_l = (u16*)(wsb + WS_DW1_LO);
  float* dep  = (float*)(wsb + WS_DEP);
  float* imgt = (float*)(wsb + WS_IMGT);
  float* mats = (float*)(wsb + WS_MATS);
  u16* fusw_h = (u16*)(wsb + WS_FUSW_HI);
  u16* fusw_l = (u16*)(wsb + WS_FUSW_LO);
  u16* bev1_h = (u16*)(wsb + WS_BEV1_HI);
  u16* hb1_h = (u16*)(wsb + WS_HB1_HI);
  u16* hb2_h = (u16*)(wsb + WS_HB2_HI);
  u16* bw2_h = (u16*)(wsb + WS_BW2_HI);
  u16* bw2_l = (u16*)(wsb + WS_BW2_LO);
  u16* bwl_h = (u16*)(wsb + WS_BWL_HI);
  u16* bwl_l = (u16*)(wsb + WS_BWL_LO);

  // prep
  featsplit<<<NBN * FH, 256, 0, stream>>>(feat, featT_h, featT_l);
  wsplit3<<<2304, 256, 0, stream>>>(cam_w1, cw1_h, cw1_l, 256, 256);
  wsplit3<<<2304, 256, 0, stream>>>(cam_w2, cw2_h, cw2_l, 256, 256);
  wsplit3<<<288, 256, 0, stream>>>(bev_w1, bw1_h, bw1_l, 128, 64);
  wsplit3<<<576, 256, 0, stream>>>(bev_w2, bw2_h, bw2_l, 128, 128);
  wsplit1<<<64, 256, 0, stream>>>(cam_wl, cwl_h, cwl_l, 64 * 256);
  wsplit1<<<256, 256, 0, stream>>>(dep_w1, dw1_h, dw1_l, 256 * 256);
  wsplit1<<<32, 256, 0, stream>>>(bev_wl, bwl_h, bwl_l, 64 * 128);
  wsplit1<<<16, 256, 0, stream>>>(fus_w, fusw_h, fusw_l, 64 * 64);
  prep_mats<<<1, 32, 0, stream>>>(rots, intrins, post_rots, mats);

  // cam encoder (MFMA, single-pass bf16, tap-paired)
  cam_mfma<<<NBN * FH, 256, 0, stream>>>(featT_h, cw1_h, cam_b1, h1_h);
  cam_mfma<<<NBN * FH, 256, 0, stream>>>(h1_h, cw2_h, cam_b2, h2_h);
  lin_mfma<<<66, 256, 0, stream>>>(h2_h, cwl_h, cam_bl, imgt);

  // depth head (MFMA from featT planes, full 3-pass for softmax accuracy)
  dep1_mfma<<<dim3(66, 4), 256, 0, stream>>>(featT_h, featT_l, dw1_h, dw1_l, dep_b1, h1d);
  dep_softmax<<<NBN * FH, 256, 0, stream>>>(h1d, dep_wl, dep_bl, dep);

  // splat (ray-grouped)
  hipMemsetAsync((void*)bev0, 0, 40960000ul, stream);
  splat<<<(NBN * ND * FW) / 4, 256, 0, stream>>>(dep, imgt, mats, trans, post_trans, bev0);

  // fusion + BEV encoder (MFMA, single-pass bf16 convs, chunk-major, tap-paired)
  fus_mfma<<<625, 256, 0, stream>>>(bev0, fusw_h, fusw_l, fus_b, bev1_h);
  bev_mfma<64><<<dim3(169, NB), 256, 0, stream>>>(bev1_h, bw1_h, bev_b1, hb1_h);
  bev_mfma<128><<<dim3(169, NB), 256, 0, stream>>>(hb1_h, bw2_h, bev_b2, hb2_h);
  out_mfma<<<625, 256, 0, stream>>>(bwl_h, bwl_l, hb2_h, bev_bl, (float*)d_out);
}

// Round 15
// 451.147 us; speedup vs baseline: 2.1305x; 1.1785x over previous
//
#include <hip/hip_runtime.h>
#include <hip/hip_bf16.h>

typedef unsigned short u16;
typedef __bf16 bf16x8 __attribute__((ext_vector_type(8)));
typedef float f32x4 __attribute__((ext_vector_type(4)));

#define NB 4
#define NCAM 6
#define NBN 24
#define CIN 256
#define CC 64
#define ND 41
#define FH 16
#define FW 44
#define NX 200
// chunk-major plane: [cc][b][y][x][32ch]; elems per plane
#define BPL ((size_t)NB * NX * NX * 32)

// ---- workspace byte offsets (overlaid; max used 164,462,592 B) ----
#define WS_FEATT_HI 0ul
#define WS_FEATT_LO 8650752ul
#define WS_H1_HI    17301504ul
#define WS_H2_HI    34603008ul
#define WS_H1D      51904512ul
#define WS_BW1_HI   69206016ul
#define WS_BW1_LO   69353472ul
#define WS_BEV0     76302336ul
#define WS_CW1_HI   117262336ul
#define WS_CW1_LO   118441984ul
#define WS_CW2_HI   119621632ul
#define WS_CW2_LO   120801280ul
#define WS_CWL_HI   121980928ul
#define WS_CWL_LO   122013696ul
#define WS_DW1_HI   122046464ul
#define WS_DW1_LO   122177536ul
#define WS_DEP      122308608ul
#define WS_IMGT     125079552ul
#define WS_MATS     129404928ul
#define WS_FUSW_HI  129406656ul
#define WS_FUSW_LO  129414848ul
#define WS_BEV1_HI  0ul            // u16 2 planes of BPL; fus->bev<64>
#define WS_HB1_HI   81920000ul     // u16 4 planes; bev<64>->bev<128>
#define WS_HB2_HI   0ul            // u16 4 planes; bev<128>->out (bev1 dead)
#define WS_BW2_HI   163840000ul
#define WS_BW2_LO   164134912ul
#define WS_BWL_HI   164429824ul
#define WS_BWL_LO   164446208ul

__device__ inline u16 f2bf_rne(float x) {
  unsigned u = __float_as_uint(x);
  unsigned r = u + 0x7fffu + ((u >> 16) & 1u);
  return (u16)(r >> 16);
}
__device__ inline float bf2f(u16 h) { return __uint_as_float(((unsigned)h) << 16); }
__device__ inline void split_bf(float x, u16& hi, u16& lo) {
  hi = f2bf_rne(x);
  lo = f2bf_rne(x - bf2f(hi));
}
__device__ inline f32x4 mfma16(bf16x8 a, bf16x8 b, f32x4 c) {
  return __builtin_amdgcn_mfma_f32_16x16x32_bf16(a, b, c, 0, 0, 0);
}
__device__ inline bf16x8 ld8(const u16* p) { return *(const bf16x8*)p; }

// ============ feat NCHW f32 -> NHWC hi/lo planes ============
__global__ __launch_bounds__(256) void featsplit(const float* __restrict__ in,
    u16* __restrict__ oh, u16* __restrict__ ol) {
  int nh = blockIdx.x;
  int n = nh >> 4, h = nh & 15;
  __shared__ float lds[256][44];
  int tid = threadIdx.x;
  for (int e = tid; e < 256 * 44; e += 256) {
    int ci = e / 44, w = e % 44;
    lds[ci][w] = in[((n * CIN + ci) * FH + h) * FW + w];
  }
  __syncthreads();
  for (int e = tid; e < 256 * 44; e += 256) {
    int w = e / 256, ci = e % 256;
    u16 hi, lo;
    split_bf(lds[ci][w], hi, lo);
    size_t o = ((size_t)((n * FH + h) * FW + w)) * 256 + ci;
    oh[o] = hi; ol[o] = lo;
  }
}

// ============ weight split 3x3 ============
__global__ __launch_bounds__(256) void wsplit3(const float* __restrict__ src,
    u16* __restrict__ dhi, u16* __restrict__ dlo, int CO, int CI_) {
  int idx = blockIdx.x * 256 + threadIdx.x;
  if (idx >= CO * CI_ * 9) return;
  int co = idx / (CI_ * 9);
  int r = idx % (CI_ * 9);
  int ci = r / 9, t = r % 9;
  u16 h, l;
  split_bf(src[idx], h, l);
  int o = (t * CO + co) * CI_ + ci;
  dhi[o] = h; dlo[o] = l;
}

// ============ weight split 1x1 ============
__global__ __launch_bounds__(256) void wsplit1(const float* __restrict__ src,
    u16* __restrict__ dhi, u16* __restrict__ dlo, int n) {
  int i = blockIdx.x * 256 + threadIdx.x;
  if (i >= n) return;
  u16 h, l;
  split_bf(src[i], h, l);
  dhi[i] = h; dlo[i] = l;
}

// ============ per-(b,n) matrices ============
__global__ void prep_mats(const float* __restrict__ rots, const float* __restrict__ intrins,
                          const float* __restrict__ post_rots, float* __restrict__ mats) {
  int bn = threadIdx.x;
  if (bn >= NBN) return;
  {
    const float* A = intrins + bn * 9;
    double a0=A[0],a1=A[1],a2=A[2],a3=A[3],a4=A[4],a5=A[5],a6=A[6],a7=A[7],a8=A[8];
    double det = a0*(a4*a8 - a5*a7) - a1*(a3*a8 - a5*a6) + a2*(a3*a7 - a4*a6);
    float inv[9];
    inv[0] = (float)((a4*a8 - a5*a7) / det);
    inv[1] = (float)((a2*a7 - a1*a8) / det);
    inv[2] = (float)((a1*a5 - a2*a4) / det);
    inv[3] = (float)((a5*a6 - a3*a8) / det);
    inv[4] = (float)((a0*a8 - a2*a6) / det);
    inv[5] = (float)((a2*a3 - a0*a5) / det);
    inv[6] = (float)((a3*a7 - a4*a6) / det);
    inv[7] = (float)((a1*a6 - a0*a7) / det);
    inv[8] = (float)((a0*a4 - a1*a3) / det);
    const float* R = rots + bn * 9;
    #pragma unroll
    for (int i = 0; i < 3; ++i)
      #pragma unroll
      for (int j = 0; j < 3; ++j) {
        float s = __fadd_rn(__fadd_rn(__fmul_rn(R[i*3+0], inv[0*3+j]),
                                      __fmul_rn(R[i*3+1], inv[1*3+j])),
                            __fmul_rn(R[i*3+2], inv[2*3+j]));
        mats[bn * 9 + i * 3 + j] = s;
      }
  }
  {
    const float* A = post_rots + bn * 9;
    double a0=A[0],a1=A[1],a2=A[2],a3=A[3],a4=A[4],a5=A[5],a6=A[6],a7=A[7],a8=A[8];
    double det = a0*(a4*a8 - a5*a7) - a1*(a3*a8 - a5*a6) + a2*(a3*a7 - a4*a6);
    float* o = mats + 216 + bn * 9;
    o[0] = (float)((a4*a8 - a5*a7) / det);
    o[1] = (float)((a2*a7 - a1*a8) / det);
    o[2] = (float)((a1*a5 - a2*a4) / det);
    o[3] = (float)((a5*a6 - a3*a8) / det);
    o[4] = (float)((a0*a8 - a2*a6) / det);
    o[5] = (float)((a2*a3 - a0*a5) / det);
    o[6] = (float)((a3*a7 - a4*a6) / det);
    o[7] = (float)((a1*a6 - a0*a7) / det);
    o[8] = (float)((a0*a4 - a1*a3) / det);
  }
}

// ============ cam 3x3 conv 256->256 + relu, MFMA bf16, tap-paired, co-split x2 ============
// Block covers 128 of 256 co (blockIdx.y): acc 24 regs, LDS 35.7 KB -> (256,4),
// grid 768 -> ~3 blocks/CU resident (was 1.5 at 16% occupancy).
__global__ __launch_bounds__(256, 4) void cam_mfma(
    const u16* __restrict__ Gh,
    const u16* __restrict__ Wh,
    const float* __restrict__ bias, u16* __restrict__ Oh) {
  int nh = blockIdx.x;
  int n = nh >> 4, h = nh & 15;
  int cog = blockIdx.y * 128;
  __shared__ u16 Ah[3 * 50 * 44];
  __shared__ u16 Bh[2][128 * 44];
  int tid = threadIdx.x;
  int wv = tid >> 6, l = tid & 63;
  int l15 = l & 15, kq = l >> 4;
  f32x4 acc[3][2] = {};
  const uint4 z4 = {0u, 0u, 0u, 0u};
  for (int cc = 0; cc < 8; ++cc) {
    __syncthreads();   // prev compute done reading Ah
    for (int e = tid; e < 600; e += 256) {
      int q = e & 3;
      int c = (e >> 2) % 50;
      int r = e / 200;
      int hh = h + r - 1, ww = c - 1;
      int off = (r * 50 + c) * 44 + q * 8;
      uint4 vh = z4;
      if (hh >= 0 && hh < FH && ww >= 0 && ww < FW) {
        size_t g = ((size_t)((n * FH + hh) * FW + ww)) * 256 + cc * 32 + q * 8;
        vh = *(const uint4*)&Gh[g];
      }
      *(uint4*)&Ah[off] = vh;
    }
    for (int p = 0; p < 5; ++p) {
      int t0 = 2 * p;
      int nt = (t0 + 1 < 9) ? 2 : 1;
      __syncthreads();
      for (int e = tid; e < nt * 512; e += 256) {
        int tp = e >> 9;
        int rem = e & 511;
        int q = rem & 3, co = rem >> 2;
        size_t g = ((size_t)((t0 + tp) * 256 + cog + co)) * 256 + cc * 32 + q * 8;
        *(uint4*)&Bh[tp][co * 44 + q * 8] = *(const uint4*)&Wh[g];
      }
      __syncthreads();
      for (int tp = 0; tp < nt; ++tp) {
        int t = t0 + tp;
        int ty = t / 3, tx = t % 3;
        bf16x8 bh[2];
        #pragma unroll
        for (int nf = 0; nf < 2; ++nf)
          bh[nf] = *(const bf16x8*)&Bh[tp][(wv * 32 + nf * 16 + l15) * 44 + kq * 8];
        #pragma unroll
        for (int mf = 0; mf < 3; ++mf) {
          int o = (ty * 50 + mf * 16 + l15 + tx) * 44 + kq * 8;
          bf16x8 ah = *(const bf16x8*)&Ah[o];
          #pragma unroll
          for (int nf = 0; nf < 2; ++nf)
            acc[mf][nf] = mfma16(ah, bh[nf], acc[mf][nf]);
        }
      }
    }
  }
  // epilogue: transpose through Bh[0] (128*44 = 5632 u16 = FW*128 exactly)
  __syncthreads();
  #pragma unroll
  for (int mf = 0; mf < 3; ++mf)
    #pragma unroll
    for (int nf = 0; nf < 2; ++nf) {
      int col = wv * 32 + nf * 16 + l15;
      float bv = bias[cog + col];
      #pragma unroll
      for (int r = 0; r < 4; ++r) {
        int x = mf * 16 + kq * 4 + r;
        if (x < FW)
          Bh[0][x * 128 + col] = f2bf_rne(fmaxf(acc[mf][nf][r] + bv, 0.f));
      }
    }
  __syncthreads();
  for (int uid = tid; uid < FW * 16; uid += 256) {
    int x = uid >> 4, c16 = uid & 15;
    *(uint4*)&Oh[(((size_t)((n * FH + h) * FW + x)) * 256) + cog + c16 * 8] =
        *(const uint4*)&Bh[0][x * 128 + c16 * 8];
  }
}

// ============ BEV 3x3 conv CI->128 + relu, MFMA bf16, tap-paired, co-split x2 ============
// Block covers 64 of 128 co (blockIdx.z): acc 64 regs (fits 4 waves/EU cap of 128,
// unlike round-9's 128-reg acc), LDS 32.0 KB -> (256,4), grid 1352 -> 4 blocks/CU.
template <int CI_>
__global__ __launch_bounds__(256, 4) void bev_mfma(
    const u16* __restrict__ Gh,
    const u16* __restrict__ Wh,
    const float* __restrict__ bias, u16* __restrict__ Oh) {
  int tile = blockIdx.x;
  int b = blockIdx.y;
  int cog = blockIdx.z * 64;
  int y0 = (tile / 13) * 16, x0 = (tile % 13) * 16;
  __shared__ u16 Ah[18 * 18 * 32];
  __shared__ u16 Bh[2][64 * 44];
  int tid = threadIdx.x;
  int wv = tid >> 6, l = tid & 63;
  int l15 = l & 15, kq = l >> 4;
  f32x4 acc[4][4] = {};
  const uint4 z4 = {0u, 0u, 0u, 0u};
  for (int cc = 0; cc < CI_ / 32; ++cc) {
    __syncthreads();   // prev compute done reading Ah
    for (int e = tid; e < 1296; e += 256) {
      int q = e & 3;
      int dx = (e >> 2) % 18;
      int dy = e / 72;
      int gy = y0 + dy - 1, gx = x0 + dx - 1;
      int row = dy * 18 + dx;
      int off = row * 32 + ((q ^ ((row >> 1) & 3)) * 8);
      uint4 vh = z4;
      if (gy >= 0 && gy < NX && gx >= 0 && gx < NX) {
        size_t g = (size_t)cc * BPL + ((size_t)((b * NX + gy) * NX + gx)) * 32 + q * 8;
        vh = *(const uint4*)&Gh[g];
      }
      *(uint4*)&Ah[off] = vh;
    }
    for (int p = 0; p < 5; ++p) {
      int t0 = 2 * p;
      int nt = (t0 + 1 < 9) ? 2 : 1;
      __syncthreads();
      for (int e = tid; e < nt * 256; e += 256) {
        int tp = e >> 8;
        int rem = e & 255;
        int q = rem & 3, co = rem >> 2;
        size_t g = ((size_t)((t0 + tp) * 128 + cog + co)) * CI_ + cc * 32 + q * 8;
        *(uint4*)&Bh[tp][co * 44 + q * 8] = *(const uint4*)&Wh[g];
      }
      __syncthreads();
      for (int tp = 0; tp < nt; ++tp) {
        int t = t0 + tp;
        int ty = t / 3, tx = t % 3;
        bf16x8 bh[4];
        #pragma unroll
        for (int nf = 0; nf < 4; ++nf)
          bh[nf] = *(const bf16x8*)&Bh[tp][(nf * 16 + l15) * 44 + kq * 8];
        #pragma unroll
        for (int mf = 0; mf < 4; ++mf) {
          int row = (wv * 4 + mf + ty) * 18 + (l15 + tx);
          int o = row * 32 + ((kq ^ ((row >> 1) & 3)) * 8);
          bf16x8 ah = *(const bf16x8*)&Ah[o];
          #pragma unroll
          for (int nf = 0; nf < 4; ++nf)
            acc[mf][nf] = mfma16(ah, bh[nf], acc[mf][nf]);
        }
      }
    }
  }
  // --- coalesced store epilogue: per-mf slice through Ah; 64 co -> 2 chunk planes ---
  u16* st = Ah;
  for (int mf = 0; mf < 4; ++mf) {
    __syncthreads();
    #pragma unroll
    for (int nf = 0; nf < 4; ++nf) {
      int co = nf * 16 + l15;
      int cw = co >> 3;
      float bv = bias[cog + co];
      #pragma unroll
      for (int r = 0; r < 4; ++r) {
        int xx = kq * 4 + r;
        int row = wv * 16 + xx;
        st[row * 64 + (((cw + row) & 7) * 8) + (co & 7)] =
            f2bf_rne(fmaxf(acc[mf][nf][r] + bv, 0.f));
      }
    }
    __syncthreads();
    #pragma unroll
    for (int k = 0; k < 2; ++k) {
      int uid = tid + k * 256;
      int pos = uid >> 3, c16 = uid & 7;
      int wvp = pos >> 4, xx = pos & 15;
      int yy = y0 + wvp * 4 + mf, gx = x0 + xx;
      if (yy < NX && gx < NX) {
        int chg = (cog >> 5) + (c16 >> 2), qq = c16 & 3;
        *(uint4*)&Oh[(size_t)chg * BPL + ((size_t)((b * NX + yy) * NX + gx)) * 32 + qq * 8] =
            *(const uint4*)&st[pos * 64 + (((c16 + pos) & 7) * 8)];
      }
    }
  }
}

// ============ cam 1x1 256->64 MFMA, single-pass bf16 ============
__global__ __launch_bounds__(256) void lin_mfma(const u16* __restrict__ Gh,
    const u16* __restrict__ Wh,
    const float* __restrict__ bias, float* __restrict__ out) {
  int wv = threadIdx.x >> 6, l = threadIdx.x & 63;
  int l15 = l & 15, kq = l >> 4;
  int pos0 = blockIdx.x * 256 + wv * 64;
  f32x4 acc[4][4] = {};
  for (int ks = 0; ks < 8; ++ks) {
    bf16x8 bh[4], ah[4];
    #pragma unroll
    for (int nf = 0; nf < 4; ++nf)
      bh[nf] = ld8(Wh + (nf * 16 + l15) * 256 + ks * 32 + kq * 8);
    #pragma unroll
    for (int mf = 0; mf < 4; ++mf)
      ah[mf] = ld8(Gh + ((size_t)(pos0 + mf * 16 + l15)) * 256 + ks * 32 + kq * 8);
    #pragma unroll
    for (int mf = 0; mf < 4; ++mf)
      #pragma unroll
      for (int nf = 0; nf < 4; ++nf)
        acc[mf][nf] = mfma16(ah[mf], bh[nf], acc[mf][nf]);
  }
  #pragma unroll
  for (int mf = 0; mf < 4; ++mf)
    #pragma unroll
    for (int nf = 0; nf < 4; ++nf) {
      float bv = bias[nf * 16 + l15];
      #pragma unroll
      for (int r = 0; r < 4; ++r) {
        int pos = pos0 + mf * 16 + kq * 4 + r;
        out[(size_t)pos * 64 + nf * 16 + l15] = acc[mf][nf][r] + bv;
      }
    }
}

// ============ dep 1x1 256->256 + relu MFMA (full 3-pass for softmax accuracy) ============
__global__ __launch_bounds__(256) void dep1_mfma(const u16* __restrict__ Gh,
    const u16* __restrict__ Gl, const u16* __restrict__ Wh, const u16* __restrict__ Wl,
    const float* __restrict__ bias, float* __restrict__ out) {
  int wv = threadIdx.x >> 6, l = threadIdx.x & 63;
  int l15 = l & 15, kq = l >> 4;
  int pos0 = blockIdx.x * 256 + wv * 64;
  int cog = blockIdx.y * 64;
  f32x4 acc[4][4] = {};
  for (int ks = 0; ks < 8; ++ks) {
    bf16x8 bh[4], bl[4], ah[4], al[4];
    #pragma unroll
    for (int nf = 0; nf < 4; ++nf) {
      int o = (cog + nf * 16 + l15) * 256 + ks * 32 + kq * 8;
      bh[nf] = ld8(Wh + o); bl[nf] = ld8(Wl + o);
    }
    #pragma unroll
    for (int mf = 0; mf < 4; ++mf) {
      size_t o = ((size_t)(pos0 + mf * 16 + l15)) * 256 + ks * 32 + kq * 8;
      ah[mf] = ld8(Gh + o); al[mf] = ld8(Gl + o);
    }
    #pragma unroll
    for (int mf = 0; mf < 4; ++mf)
      #pragma unroll
      for (int nf = 0; nf < 4; ++nf) {
        acc[mf][nf] = mfma16(ah[mf], bh[nf], acc[mf][nf]);
        acc[mf][nf] = mfma16(ah[mf], bl[nf], acc[mf][nf]);
        acc[mf][nf] = mfma16(al[mf], bh[nf], acc[mf][nf]);
      }
  }
  #pragma unroll
  for (int mf = 0; mf < 4; ++mf)
    #pragma unroll
    for (int nf = 0; nf < 4; ++nf) {
      int co = cog + nf * 16 + l15;
      float bv = bias[co];
      #pragma unroll
      for (int r = 0; r < 4; ++r) {
        int pos = pos0 + mf * 16 + kq * 4 + r;
        out[(size_t)pos * 256 + co] = fmaxf(acc[mf][nf][r] + bv, 0.f);
      }
    }
}

// ============ fus 1x1 64->64 MFMA (bev0 f32 split in-reg, chunk-major bf16 out) ============
__global__ __launch_bounds__(256) void fus_mfma(const float* __restrict__ in,
    const u16* __restrict__ Wh, const u16* __restrict__ Wl,
    const float* __restrict__ bias, u16* __restrict__ oh) {
  int wv = threadIdx.x >> 6, l = threadIdx.x & 63;
  int l15 = l & 15, kq = l >> 4;
  int pos0 = blockIdx.x * 256 + wv * 64;
  f32x4 acc[4][4] = {};
  for (int ks = 0; ks < 2; ++ks) {
    bf16x8 bh[4], bl[4], ah[4], al[4];
    #pragma unroll
    for (int nf = 0; nf < 4; ++nf) {
      int o = (nf * 16 + l15) * 64 + ks * 32 + kq * 8;
      bh[nf] = ld8(Wh + o); bl[nf] = ld8(Wl + o);
    }
    #pragma unroll
    for (int mf = 0; mf < 4; ++mf) {
      size_t o = ((size_t)(pos0 + mf * 16 + l15)) * 64 + ks * 32 + kq * 8;
      float4 v0 = *(const float4*)&in[o];
      float4 v1 = *(const float4*)&in[o + 4];
      float xs[8] = {v0.x, v0.y, v0.z, v0.w, v1.x, v1.y, v1.z, v1.w};
      u16 th[8], tl[8];
      #pragma unroll
      for (int i = 0; i < 8; ++i) split_bf(xs[i], th[i], tl[i]);
      ah[mf] = *(const bf16x8*)th;
      al[mf] = *(const bf16x8*)tl;
    }
    #pragma unroll
    for (int mf = 0; mf < 4; ++mf)
      #pragma unroll
      for (int nf = 0; nf < 4; ++nf) {
        acc[mf][nf] = mfma16(ah[mf], bh[nf], acc[mf][nf]);
        acc[mf][nf] = mfma16(ah[mf], bl[nf], acc[mf][nf]);
        acc[mf][nf] = mfma16(al[mf], bh[nf], acc[mf][nf]);
      }
  }
  #pragma unroll
  for (int mf = 0; mf < 4; ++mf)
    #pragma unroll
    for (int nf = 0; nf < 4; ++nf) {
      int c = nf * 16 + l15;
      int ch = c >> 5, cw = c & 31;
      float bv = bias[c];
      #pragma unroll
      for (int r = 0; r < 4; ++r) {
        int pos = pos0 + mf * 16 + kq * 4 + r;
        oh[(size_t)ch * BPL + (size_t)pos * 32 + cw] = f2bf_rne(acc[mf][nf][r] + bv);
      }
    }
}

// ============ out 1x1 128->64 MFMA (split weights, chunk-major bf16 acts) ============
__global__ __launch_bounds__(256) void out_mfma(const u16* __restrict__ Wh,
    const u16* __restrict__ Wl, const u16* __restrict__ Gh,
    const float* __restrict__ bias, float* __restrict__ out) {
  int wv = threadIdx.x >> 6, l = threadIdx.x & 63;
  int l15 = l & 15, kq = l >> 4;
  int pos0 = blockIdx.x * 256 + wv * 64;
  f32x4 acc[4][4] = {};
  for (int ks = 0; ks < 4; ++ks) {
    bf16x8 ah[4], al[4], bh[4];
    #pragma unroll
    for (int mf = 0; mf < 4; ++mf) {
      int o = (mf * 16 + l15) * 128 + ks * 32 + kq * 8;
      ah[mf] = ld8(Wh + o); al[mf] = ld8(Wl + o);
    }
    #pragma unroll
    for (int nf = 0; nf < 4; ++nf)
      bh[nf] = ld8(Gh + (size_t)ks * BPL + ((size_t)(pos0 + nf * 16 + l15)) * 32 + kq * 8);
    #pragma unroll
    for (int mf = 0; mf < 4; ++mf)
      #pragma unroll
      for (int nf = 0; nf < 4; ++nf) {
        acc[mf][nf] = mfma16(ah[mf], bh[nf], acc[mf][nf]);
        acc[mf][nf] = mfma16(al[mf], bh[nf], acc[mf][nf]);
      }
  }
  #pragma unroll
  for (int mf = 0; mf < 4; ++mf)
    #pragma unroll
    for (int r = 0; r < 4; ++r) {
      int co = mf * 16 + kq * 4 + r;
      float bv = bias[co];
      #pragma unroll
      for (int nf = 0; nf < 4; ++nf) {
        int pos = pos0 + nf * 16 + l15;
        int b = pos / 40000;
        int xy = pos - b * 40000;
        out[((size_t)(b * CC + co)) * 40000 + xy] = acc[mf][nf][r] + bv;
      }
    }
}

// ============ depth 1x1 conv 256->41 + softmax ============
__global__ __launch_bounds__(256) void dep_softmax(const float* __restrict__ in,
    const float* __restrict__ wt, const float* __restrict__ bias, float* __restrict__ depth) {
  int nh = blockIdx.x;
  int n = nh >> 4, h = nh & 15;
  __shared__ float lds[256][49];
  __shared__ float lg[ND][FW];
  int tid = threadIdx.x;
  for (int e = tid; e < 256 * 48; e += 256) {
    int ci = e % 256, w = e / 256;
    lds[ci][w] = (w < FW) ? in[((size_t)((n * FH + h) * FW + w)) * 256 + ci] : 0.f;
  }
  __syncthreads();
  int co = tid >> 2, wseg = tid & 3;
  int ob = wseg * 12;
  int nj = (wseg == 3) ? 8 : 12;
  if (co < ND) {
    float acc[12];
    #pragma unroll
    for (int j = 0; j < 12; ++j) acc[j] = 0.f;
    const float* wp = wt + co * 256;
    for (int ci = 0; ci < 256; ++ci) {
      float wv = wp[ci];
      #pragma unroll
      for (int j = 0; j < 12; ++j) acc[j] += wv * lds[ci][ob + j];
    }
    float b = bias[co];
    for (int j = 0; j < nj; ++j) lg[co][ob + j] = acc[j] + b;
  }
  __syncthreads();
  if (tid < FW) {
    int w = tid;
    float m = lg[0][w];
    #pragma unroll
    for (int d = 1; d < ND; ++d) m = fmaxf(m, lg[d][w]);
    float s = 0.f;
    #pragma unroll
    for (int d = 0; d < ND; ++d) s += expf(lg[d][w] - m);
    #pragma unroll
    for (int d = 0; d < ND; ++d)
      depth[((n * ND + d) * FH + h) * FW + w] = expf(lg[d][w] - m) / s;
  }
}

// ============ splat: one wave per (bn,d,w) ray group; run-length cell flush ============
__global__ __launch_bounds__(256) void splat(const float* __restrict__ depth,
    const float* __restrict__ img, const float* __restrict__ mats,
    const float* __restrict__ trans, const float* __restrict__ ptrans,
    float* __restrict__ bev0) {
  int gid = blockIdx.x * 4 + (threadIdx.x >> 6);
  int c = threadIdx.x & 63;
  int w = gid % FW;
  int t = gid / FW;
  int d = t % ND;
  int bn = t / ND;
  int b = bn / NCAM;
  float fx = (w == FW - 1) ? 703.0f : (float)((double)w * (703.0 / 43.0));
  float fz = (float)(4 + d);
  const float* pt = ptrans + bn * 3;
  const float* P = mats + 216 + bn * 9;
  const float* M = mats + bn * 9;
  const float* tr = trans + bn * 3;
  float px = __fsub_rn(fx, pt[0]);
  float pz = __fsub_rn(fz, pt[2]);
  const float* dp = depth + ((size_t)(bn * ND + d) * FH) * FW + w;
  const float* ip = img + ((size_t)(bn * FH) * FW + w) * CC + c;
  int cell = -1;
  float acc = 0.f;
  for (int h = 0; h < FH; ++h) {
    float fy = (float)(17 * h);
    float py = __fsub_rn(fy, pt[1]);
    float q0 = __fadd_rn(__fadd_rn(__fmul_rn(P[0], px), __fmul_rn(P[1], py)), __fmul_rn(P[2], pz));
    float q1 = __fadd_rn(__fadd_rn(__fmul_rn(P[3], px), __fmul_rn(P[4], py)), __fmul_rn(P[5], pz));
    float q2 = __fadd_rn(__fadd_rn(__fmul_rn(P[6], px), __fmul_rn(P[7], py)), __fmul_rn(P[8], pz));
    float r0 = __fmul_rn(q0, q2), r1 = __fmul_rn(q1, q2), r2 = q2;
    float u0 = __fadd_rn(__fadd_rn(__fadd_rn(__fmul_rn(M[0], r0), __fmul_rn(M[1], r1)), __fmul_rn(M[2], r2)), tr[0]);
    float u1 = __fadd_rn(__fadd_rn(__fadd_rn(__fmul_rn(M[3], r0), __fmul_rn(M[4], r1)), __fmul_rn(M[5], r2)), tr[1]);
    float u2 = __fadd_rn(__fadd_rn(__fadd_rn(__fmul_rn(M[6], r0), __fmul_rn(M[7], r1)), __fmul_rn(M[8], r2)), tr[2]);
    int gx = (int)__fmul_rn(__fadd_rn(u0, 50.0f), 2.0f);
    int gy = (int)__fmul_rn(__fadd_rn(u1, 50.0f), 2.0f);
    int gz = (int)__fdiv_rn(__fadd_rn(u2, 10.0f), 20.0f);
    bool kept = (gx >= 0 && gx < NX && gy >= 0 && gy < NX && gz == 0);
    int c2 = kept ? (b * NX + gx) * NX + gy : -1;
    if (c2 != cell) {
      if (cell >= 0) atomicAdd(&bev0[(size_t)cell * CC + c], acc);
      cell = c2;
      acc = 0.f;
    }
    if (kept)
      acc = __fadd_rn(acc, __fmul_rn(dp[h * FW], ip[(size_t)h * FW * CC]));
  }
  if (cell >= 0) atomicAdd(&bev0[(size_t)cell * CC + c], acc);
}

extern "C" void kernel_launch(void* const* d_in, const int* in_sizes, int n_in,
                              void* d_out, int out_size, void* d_ws, size_t ws_size,
                              hipStream_t stream) {
  const float* feat       = (const float*)d_in[0];
  const float* rots       = (const float*)d_in[1];
  const float* trans      = (const float*)d_in[2];
  const float* intrins    = (const float*)d_in[3];
  const float* post_trans = (const float*)d_in[5];
  const float* post_rots  = (const float*)d_in[6];
  const float* cam_w1 = (const float*)d_in[7];
  const float* cam_b1 = (const float*)d_in[8];
  const float* cam_w2 = (const float*)d_in[9];
  const float* cam_b2 = (const float*)d_in[10];
  const float* cam_wl = (const float*)d_in[11];
  const float* cam_bl = (const float*)d_in[12];
  const float* dep_w1 = (const float*)d_in[13];
  const float* dep_b1 = (const float*)d_in[14];
  const float* dep_wl = (const float*)d_in[15];
  const float* dep_bl = (const float*)d_in[16];
  const float* fus_w  = (const float*)d_in[17];
  const float* fus_b  = (const float*)d_in[18];
  const float* bev_w1 = (const float*)d_in[19];
  const float* bev_b1 = (const float*)d_in[20];
  const float* bev_w2 = (const float*)d_in[21];
  const float* bev_b2 = (const float*)d_in[22];
  const float* bev_wl = (const float*)d_in[23];
  const float* bev_bl = (const float*)d_in[24];

  char* wsb = (char*)d_ws;
  u16* featT_h = (u16*)(wsb + WS_FEATT_HI);
  u16* featT_l = (u16*)(wsb + WS_FEATT_LO);
  u16* h1_h = (u16*)(wsb + WS_H1_HI);
  u16* h2_h = (u16*)(wsb + WS_H2_HI);
  float* h1d = (float*)(wsb + WS_H1D);
  u16* bw1_h = (u16*)(wsb + WS_BW1_HI);
  u16* bw1_l = (u16*)(wsb + WS_BW1_LO);
  float* bev0 = (float*)(wsb + WS_BEV0);
  u16* cw1_h = (u16*)(wsb + WS_CW1_HI);
  u16* cw1_l = (u16*)(wsb + WS_CW1_LO);
  u16* cw2_h = (u16*)(wsb + WS_CW2_HI);
  u16* cw2_l = (u16*)(wsb + WS_CW2_LO);
  u16* cwl_h = (u16*)(wsb + WS_CWL_HI);
  u16* cwl_l = (u16*)(wsb + WS_CWL_LO);
  u16* dw1_h = (u16*)(wsb + WS_DW1_HI);
  u16* dw1_l = (u16*)(wsb + WS_DW1_LO);
  float* dep  = (float*)(wsb + WS_DEP);
  float* imgt = (float*)(wsb + WS_IMGT);
  float* mats = (float*)(wsb + WS_MATS);
  u16* fusw_h = (u16*)(wsb + WS_FUSW_HI);
  u16* fusw_l = (u16*)(wsb + WS_FUSW_LO);
  u16* bev1_h = (u16*)(wsb + WS_BEV1_HI);
  u16* hb1_h = (u16*)(wsb + WS_HB1_HI);
  u16* hb2_h = (u16*)(wsb + WS_HB2_HI);
  u16* bw2_h = (u16*)(wsb + WS_BW2_HI);
  u16* bw2_l = (u16*)(wsb + WS_BW2_LO);
  u16* bwl_h = (u16*)(wsb + WS_BWL_HI);
  u16* bwl_l = (u16*)(wsb + WS_BWL_LO);

  // prep
  featsplit<<<NBN * FH, 256, 0, stream>>>(feat, featT_h, featT_l);
  wsplit3<<<2304, 256, 0, stream>>>(cam_w1, cw1_h, cw1_l, 256, 256);
  wsplit3<<<2304, 256, 0, stream>>>(cam_w2, cw2_h, cw2_l, 256, 256);
  wsplit3<<<288, 256, 0, stream>>>(bev_w1, bw1_h, bw1_l, 128, 64);
  wsplit3<<<576, 256, 0, stream>>>(bev_w2, bw2_h, bw2_l, 128, 128);
  wsplit1<<<64, 256, 0, stream>>>(cam_wl, cwl_h, cwl_l, 64 * 256);
  wsplit1<<<256, 256, 0, stream>>>(dep_w1, dw1_h, dw1_l, 256 * 256);
  wsplit1<<<32, 256, 0, stream>>>(bev_wl, bwl_h, bwl_l, 64 * 128);
  wsplit1<<<16, 256, 0, stream>>>(fus_w, fusw_h, fusw_l, 64 * 64);
  prep_mats<<<1, 32, 0, stream>>>(rots, intrins, post_rots, mats);

  // cam encoder (MFMA, bf16, tap-paired, co-split x2)
  cam_mfma<<<dim3(NBN * FH, 2), 256, 0, stream>>>(featT_h, cw1_h, cam_b1, h1_h);
  cam_mfma<<<dim3(NBN * FH, 2), 256, 0, stream>>>(h1_h, cw2_h, cam_b2, h2_h);
  lin_mfma<<<66, 256, 0, stream>>>(h2_h, cwl_h, cam_bl, imgt);

  // depth head (MFMA from featT planes, full 3-pass for softmax accuracy)
  dep1_mfma<<<dim3(66, 4), 256, 0, stream>>>(featT_h, featT_l, dw1_h, dw1_l, dep_b1, h1d);
  dep_softmax<<<NBN * FH, 256, 0, stream>>>(h1d, dep_wl, dep_bl, dep);

  // splat (ray-grouped)
  hipMemsetAsync((void*)bev0, 0, 40960000ul, stream);
  splat<<<(NBN * ND * FW) / 4, 256, 0, stream>>>(dep, imgt, mats, trans, post_trans, bev0);

  // fusion + BEV encoder (MFMA, bf16 convs, chunk-major, tap-paired, co-split x2)
  fus_mfma<<<625, 256, 0, stream>>>(bev0, fusw_h, fusw_l, fus_b, bev1_h);
  bev_mfma<64><<<dim3(169, NB, 2), 256, 0, stream>>>(bev1_h, bw1_h, bev_b1, hb1_h);
  bev_mfma<128><<<dim3(169, NB, 2), 256, 0, stream>>>(hb1_h, bw2_h, bev_b2, hb2_h);
  out_mfma<<<625, 256, 0, stream>>>(bwl_h, bwl_l, hb2_h, bev_bl, (float*)d_out);
}